// Round 3
// baseline (358.956 us; speedup 1.0000x reference)
//
#include <hip/hip_runtime.h>
#include <hip/hip_bf16.h>
#include <math.h>

typedef __attribute__((ext_vector_type(8))) short short8;
typedef __attribute__((ext_vector_type(4))) float floatx4;
typedef __attribute__((ext_vector_type(4))) int intx4;

#define ATT_SCALE 0.865617024533378f  /* 0.6 * log2(e) */
#define C_ABS 0.6666666666667f        /* 0.4 / 0.6 */
#define PCLAMP 86.5f                  /* ~60 nats in log2 domain */

__device__ __forceinline__ float bf2f(unsigned short u) {
  union { unsigned int i; float f; } v; v.i = ((unsigned int)u) << 16; return v.f;
}
__device__ __forceinline__ unsigned short f2bf(float f) {
  union { float f; unsigned int u; } v; v.f = f;
  unsigned int r = (v.u + 0x7fffu + ((v.u >> 16) & 1u)) >> 16;
  return (unsigned short)r;
}
__device__ __forceinline__ int imin(int a, int b) { return a < b ? a : b; }
__device__ __forceinline__ int iclamp(int v, int lo, int hi) {
  return v < lo ? lo : (v > hi ? hi : v);
}
__device__ __forceinline__ float uasf(unsigned int u) {
  union { unsigned int i; float f; } v; v.i = u; return v.f;
}
__device__ __forceinline__ float exp2fast(float x) {
#if __has_builtin(__builtin_amdgcn_exp2f)
  return __builtin_amdgcn_exp2f(x);
#else
  return exp2f(x);
#endif
}
// 8-lane group sum: xor1/xor2 via quad_perm DPP, xor4 via ds_swizzle.
__device__ __forceinline__ float sum8(float x) {
  union { float f; int i; } a, t;
  a.f = x;
  t.i = __builtin_amdgcn_update_dpp(0, a.i, 0xB1, 0xF, 0xF, true); a.f += t.f;  // xor1
  t.i = __builtin_amdgcn_update_dpp(0, a.i, 0x4E, 0xF, 0xF, true); a.f += t.f;  // xor2
  t.i = __builtin_amdgcn_ds_swizzle(a.i, 0x101F); a.f += t.f;                   // xor4
  return a.f;
}

// ---------------- sentinel: ws too small ----------------
__global__ void k_sentinel(float* out, float val) {
  if (threadIdx.x < 64) out[threadIdx.x] = val;
}

// ---------------- small-vector conversion segments ----------------
struct CvtSegs {
  const void* src[10];
  unsigned short* dst[10];
  int len[10];
};

// ---- mega prep: per-block dtype probe, then cvt8 | cvt_small | trans | hist --
__global__ void k_prep(const void* __restrict__ x, unsigned short* __restrict__ x_c,
                       int n8, CvtSegs segs,
                       const void* __restrict__ s0, const void* __restrict__ s1,
                       const void* __restrict__ s2, const void* __restrict__ s3,
                       unsigned short* __restrict__ d0, unsigned short* __restrict__ d1,
                       unsigned short* __restrict__ d2, unsigned short* __restrict__ d3,
                       const int* __restrict__ edst, int* deg, int E, int N,
                       int* dflag, float* __restrict__ att1s, float* __restrict__ att2s,
                       int nCvt8, int nTransB) {
  __shared__ int csh;
  if (threadIdx.x == 0) csh = 0;
  __syncthreads();
  {
    unsigned short u = ((const unsigned short*)x)[threadIdx.x];
    int e = (u >> 7) & 0xFF;
    atomicAdd(&csh, (u == 0) || (e >= 100 && e <= 145));
  }
  __syncthreads();
  int isf = (csh < 240);

  int b = blockIdx.x;
  if (b < nCvt8) {
    if (!isf) return;                       // bf16 input: x used directly
    int i = b * 256 + threadIdx.x;
    if (i >= n8) return;
    const float* s = (const float*)x + (size_t)i * 8;
    ushort4 a, c;
    a.x = f2bf(s[0]); a.y = f2bf(s[1]); a.z = f2bf(s[2]); a.w = f2bf(s[3]);
    c.x = f2bf(s[4]); c.y = f2bf(s[5]); c.z = f2bf(s[6]); c.w = f2bf(s[7]);
    ((ushort4*)x_c)[i * 2] = a;
    ((ushort4*)x_c)[i * 2 + 1] = c;
    return;
  }
  b -= nCvt8;
  if (b < 10) {
    if (b == 0 && threadIdx.x == 0) dflag[0] = isf;
    int i = threadIdx.x;
    if (i < segs.len[b]) {
      float v = isf ? ((const float*)segs.src[b])[i]
                    : bf2f(((const unsigned short*)segs.src[b])[i]);
      segs.dst[b][i] = f2bf(v);
      // scaled f32 attention coefficients (exp2-domain scores)
      if (b == 2) att1s[i] = v * ATT_SCALE;
      if (b == 6) att2s[i] = v * ATT_SCALE;
    }
    return;
  }
  b -= 10;
  if (b < nTransB) {
    int idx = b * 256 + threadIdx.x;  // flat over 98304 elements
    const void* src; unsigned short* dst; int R, C, loc;
    if (idx < 32768)      { src = s0; dst = d0; R = 128; C = 256; loc = idx; }
    else if (idx < 65536) { src = s1; dst = d1; R = 128; C = 256; loc = idx - 32768; }
    else if (idx < 81920) { src = s2; dst = d2; R = 256; C = 64;  loc = idx - 65536; }
    else                  { src = s3; dst = d3; R = 256; C = 64;  loc = idx - 81920; }
    unsigned short u = isf ? f2bf(((const float*)src)[loc])
                           : ((const unsigned short*)src)[loc];
    int r = loc / C, cc = loc - r * C;
    dst[cc * R + r] = u;
    return;
  }
  b -= nTransB;
  // histogram: 4 edges per thread (independent atomic chains) [R8-measured]
  int base = b * 1024 + threadIdx.x;
#pragma unroll
  for (int k = 0; k < 4; ++k) {
    int e = base + k * 256;
    if (e < E) atomicAdd(&deg[iclamp(edst[e], 0, N - 1)], 1);
  }
}

// ---------------- scan stage 1: per-1024 block sums + LDS-staged deg hist ----
// capacity = roundup4(deg + 1) so every CSR row starts 16B-aligned in colx.
__global__ __launch_bounds__(1024) void k_scan1(const int* __restrict__ deg, int* bsum,
                                                int* dhist, int N) {
  __shared__ int sm[1024];
  __shared__ int lh[256];
  int tid = threadIdx.x;
  if (tid < 256) lh[tid] = 0;
  __syncthreads();
  int i = blockIdx.x * 1024 + tid;
  int d = (i < N) ? deg[i] : 0;
  if (i < N) atomicAdd(&lh[imin(d, 255)], 1);
  sm[tid] = (i < N) ? ((d + 4) & ~3) : 0;
  __syncthreads();
  for (int off = 512; off > 0; off >>= 1) {
    if (tid < off) sm[tid] += sm[tid + off];
    __syncthreads();
  }
  if (tid == 0) bsum[blockIdx.x] = sm[0];
  if (tid < 256 && lh[tid]) atomicAdd(&dhist[tid], lh[tid]);
}

// ---- scan stage 2: Hillis-Steele + inline bsum prefix -> rowptr & cursor ----
// Block 0 additionally exclusive-scans the 256-bin degree histogram -> dcur.
__global__ __launch_bounds__(1024) void k_scan3(const int* __restrict__ deg,
                                                const int* __restrict__ bsum,
                                                const int* __restrict__ dhist,
                                                int* dcur,
                                                int* rowptr, int* cursor, int N) {
  __shared__ int sm[1024];
  __shared__ int boff;
  __shared__ int hsc[256];
  int tid = threadIdx.x;
  if (tid == 0) {
    int r = 0;
    for (int b = 0; b < blockIdx.x; ++b) r += bsum[b];
    boff = r;
  }
  int i = blockIdx.x * 1024 + tid;
  int v = (i < N) ? ((deg[i] + 4) & ~3) : 0;
  sm[tid] = v;
  __syncthreads();
  for (int off = 1; off < 1024; off <<= 1) {
    int t = (tid >= off) ? sm[tid - off] : 0;
    __syncthreads();
    sm[tid] += t;
    __syncthreads();
  }
  if (i < N) {
    int ex = sm[tid] - v + boff;
    rowptr[i] = ex;
    cursor[i] = ex;
    if (i == N - 1) rowptr[N] = ex + v;
  }
  // ---- block 0: exclusive scan of dhist into dcur ----
  int hv = 0;
  if (blockIdx.x == 0 && tid < 256) { hv = dhist[tid]; hsc[tid] = hv; }
  __syncthreads();
  for (int off = 1; off < 256; off <<= 1) {
    int t = 0;
    if (blockIdx.x == 0 && tid < 256 && tid >= off) t = hsc[tid - off];
    __syncthreads();
    if (blockIdx.x == 0 && tid < 256) hsc[tid] += t;
    __syncthreads();
  }
  if (blockIdx.x == 0 && tid < 256) dcur[tid] = hsc[tid] - hv;
}

// ------ dual GEMM body, register-resident B + row loop (PF=1) ------
template <int K, int CT, int RT>
__device__ __forceinline__ void gemm2r_body(
    int bx, int by, int tid,
    const unsigned short* __restrict__ A,
    const unsigned short* __restrict__ BTl, const unsigned short* __restrict__ BTr,
    const unsigned short* __restrict__ bl, const unsigned short* __restrict__ br,
    unsigned short* __restrict__ outl, unsigned short* __restrict__ outr,
    int Nrows, int M) {
  constexpr int KI = K / 32;
  int lane = tid & 63;
  int wave = tid >> 6;
  int r = lane & 15, q = lane >> 4;
  int col0 = by * (4 * CT * 16) + wave * (CT * 16);
  int row0 = bx * (16 * RT);
  short8 Bl[KI][CT], Br[KI][CT];
#pragma unroll
  for (int t = 0; t < CT; ++t) {
    const unsigned short* bpl = BTl + (size_t)(col0 + t * 16 + r) * K + q * 8;
    const unsigned short* bpr = BTr + (size_t)(col0 + t * 16 + r) * K + q * 8;
#pragma unroll
    for (int k = 0; k < KI; ++k) {
      Bl[k][t] = *reinterpret_cast<const short8*>(bpl + k * 32);
      Br[k][t] = *reinterpret_cast<const short8*>(bpr + k * 32);
    }
  }
  float bvl[CT], bvr[CT];
#pragma unroll
  for (int t = 0; t < CT; ++t) {
    bvl[t] = bf2f(bl[col0 + t * 16 + r]);
    bvr[t] = bf2f(br[col0 + t * 16 + r]);
  }
  short8 a[KI], an[KI];
  {
    int ar0 = imin(row0 + r, Nrows - 1);
    const unsigned short* Ap = A + (size_t)ar0 * K + q * 8;
#pragma unroll
    for (int k = 0; k < KI; ++k) a[k] = *reinterpret_cast<const short8*>(Ap + k * 32);
  }
  for (int rt = 0; rt < RT; ++rt) {
    if (rt + 1 < RT) {
      int arn = imin(row0 + (rt + 1) * 16 + r, Nrows - 1);
      const unsigned short* Apn = A + (size_t)arn * K + q * 8;
#pragma unroll
      for (int k = 0; k < KI; ++k) an[k] = *reinterpret_cast<const short8*>(Apn + k * 32);
    }
    floatx4 accl[CT], accr[CT];
#pragma unroll
    for (int t = 0; t < CT; ++t) {
      accl[t] = (floatx4){0.f, 0.f, 0.f, 0.f};
      accr[t] = (floatx4){0.f, 0.f, 0.f, 0.f};
    }
#pragma unroll
    for (int k = 0; k < KI; ++k) {
#pragma unroll
      for (int t = 0; t < CT; ++t) {
        accl[t] = __builtin_amdgcn_mfma_f32_16x16x32_bf16(a[k], Bl[k][t], accl[t], 0, 0, 0);
        accr[t] = __builtin_amdgcn_mfma_f32_16x16x32_bf16(a[k], Br[k][t], accr[t], 0, 0, 0);
      }
    }
#pragma unroll
    for (int t = 0; t < CT; ++t) {
      int col = col0 + t * 16 + r;
#pragma unroll
      for (int rr = 0; rr < 4; ++rr) {
        int row = row0 + rt * 16 + q * 4 + rr;
        if (row < Nrows) {
          outl[(size_t)row * M + col] = f2bf(accl[t][rr] + bvl[t]);
          outr[(size_t)row * M + col] = f2bf(accr[t][rr] + bvr[t]);
        }
      }
    }
#pragma unroll
    for (int k = 0; k < KI; ++k) a[k] = an[k];
  }
}

// ------ phase1: INTERLEAVED layer-1 GEMM || scatter (role by block parity) ----
// Scatter blocks also do the degree-bucketed node ordering (LDS-staged counting
// sort scatter) and CSR pad-fill.
__global__ __launch_bounds__(256) void k_phase1(
    const unsigned short* __restrict__ A0, const unsigned short* __restrict__ A1,
    const int* __restrict__ dflag,
    const unsigned short* __restrict__ BTl, const unsigned short* __restrict__ BTr,
    const unsigned short* __restrict__ bl, const unsigned short* __restrict__ br,
    unsigned short* __restrict__ outl, unsigned short* __restrict__ outr,
    int Nrows, int M, int nG, int nS,
    const int* __restrict__ esrc, const int* __restrict__ edst,
    const int* __restrict__ rowptr, const int* __restrict__ deg,
    int* cursor, int* colx, int* dcur, int* order, int E, int N) {
  int b = blockIdx.x;
  int m2 = 2 * imin(nG, nS);
  bool isG;
  int idx;
  if (b < m2) { isG = (b & 1) == 0; idx = b >> 1; }
  else        { isG = nG > nS;      idx = imin(nG, nS) + (b - m2); }
  if (isG) {
    const unsigned short* A = dflag[0] ? A1 : A0;
    gemm2r_body<128, 2, 8>(idx >> 1, idx & 1, threadIdx.x, A, BTl, BTr, bl, br,
                           outl, outr, Nrows, M);
    return;
  }
  // ---- scatter role ----
  __shared__ int scnt[256];
  __shared__ int sbase[256];
  int ET = E + N;
  int ETcap = E + 4 * N;
  int base = idx * 1024 + threadIdx.x;
  if (threadIdx.x < 256) scnt[threadIdx.x] = 0;
  __syncthreads();
  // edges: 4 per thread (independent atomic chains)
#pragma unroll
  for (int k = 0; k < 4; ++k) {
    int e = base + k * 256;
    if (e < E) {
      int s = iclamp(esrc[e], 0, N - 1), d = iclamp(edst[e], 0, N - 1);
      int pos = atomicAdd(&cursor[d], 1);
      colx[iclamp(pos, 0, ETcap - 1)] = s;
    }
  }
  // nodes: self-loop slot + pad fill + degree-bin local index (static slots)
  bool n0 = false, n1 = false, n2 = false, n3 = false;
  int i0 = 0, i1 = 0, i2 = 0, i3 = 0, b0 = 0, b1 = 0, b2 = 0, b3 = 0;
  int l0 = 0, l1 = 0, l2 = 0, l3 = 0;
#define NODEK(nk, ik, bk, lk, KK) { int e = base + KK * 256;                  \
    if (e >= E && e < ET) { int i = e - E; int bg = rowptr[i]; int dv = deg[i]; \
      colx[bg + dv] = i; int cap = rowptr[i + 1];                             \
      for (int j = bg + dv + 1; j < cap; ++j) colx[j] = 0;                    \
      ik = i; bk = imin(dv, 255); lk = atomicAdd(&scnt[bk], 1); nk = true; } }
  NODEK(n0, i0, b0, l0, 0) NODEK(n1, i1, b1, l1, 1)
  NODEK(n2, i2, b2, l2, 2) NODEK(n3, i3, b3, l3, 3)
#undef NODEK
  __syncthreads();
  if (threadIdx.x < 256 && scnt[threadIdx.x])
    sbase[threadIdx.x] = atomicAdd(&dcur[threadIdx.x], scnt[threadIdx.x]);
  __syncthreads();
  if (n0) order[sbase[b0] + l0] = i0;
  if (n1) order[sbase[b1] + l1] = i1;
  if (n2) order[sbase[b2] + l2] = i2;
  if (n3) order[sbase[b3] + l3] = i3;
}

// ---------------- layer-2 GEMM ----------------
__global__ __launch_bounds__(256) void k_gemm2r_l2(
    const unsigned short* __restrict__ A,
    const unsigned short* __restrict__ BTl, const unsigned short* __restrict__ BTr,
    const unsigned short* __restrict__ bl, const unsigned short* __restrict__ br,
    unsigned short* __restrict__ outl, unsigned short* __restrict__ outr,
    int Nrows, int M) {
  gemm2r_body<256, 1, 4>(blockIdx.x, 0, threadIdx.x, A, BTl, BTr, bl, br,
                         outl, outr, Nrows, M);
}

// One edge-slot: unpack 8 bf16 -> q=fma(a,v,ad) -> score p (exp2 domain) ->
// 8-lane reduce -> masked exp2 -> accumulate l, o0..o7.
#define AGG1(U, KK, REM)                                                     \
  {                                                                          \
    float v0 = uasf(U.x << 16), v1 = uasf(U.x & 0xffff0000u);                \
    float v2 = uasf(U.y << 16), v3 = uasf(U.y & 0xffff0000u);                \
    float v4 = uasf(U.z << 16), v5 = uasf(U.z & 0xffff0000u);                \
    float v6 = uasf(U.w << 16), v7 = uasf(U.w & 0xffff0000u);                \
    float q0 = fmaf(a0, v0, ad0), q1 = fmaf(a1, v1, ad1);                    \
    float q2 = fmaf(a2, v2, ad2), q3 = fmaf(a3, v3, ad3);                    \
    float q4 = fmaf(a4, v4, ad4), q5 = fmaf(a5, v5, ad5);                    \
    float q6 = fmaf(a6, v6, ad6), q7 = fmaf(a7, v7, ad7);                    \
    float p = ((q0 + q1) + (q2 + q3)) + ((q4 + q5) + (q6 + q7));             \
    p = fmaf(c0, fabsf(q0), p); p = fmaf(c1, fabsf(q1), p);                  \
    p = fmaf(c2, fabsf(q2), p); p = fmaf(c3, fabsf(q3), p);                  \
    p = fmaf(c4, fabsf(q4), p); p = fmaf(c5, fabsf(q5), p);                  \
    p = fmaf(c6, fabsf(q6), p); p = fmaf(c7, fabsf(q7), p);                  \
    p = sum8(p);                                                             \
    float lim = (KK < (REM)) ? PCLAMP : -INFINITY;                           \
    p = fminf(p, lim);                                                       \
    float w = exp2fast(p);                                                   \
    l += w;                                                                  \
    o0 = fmaf(w, v0, o0); o1 = fmaf(w, v1, o1);                              \
    o2 = fmaf(w, v2, o2); o3 = fmaf(w, v3, o3);                              \
    o4 = fmaf(w, v4, o4); o5 = fmaf(w, v5, o5);                              \
    o6 = fmaf(w, v6, o6); o7 = fmaf(w, v7, o7);                              \
  }

// ------- unified aggregation body: LPD lanes per dst, 8 channels per lane ----
// Persistent strided waves over dst-groups in DESCENDING degree order
// (order[] is ascending; indexed reversed): heaviest rows are scheduled
// first across the exact-fill grid, light rows drain the tail; strided
// assignment gives each wave a heavy+light mix (equal totals). 8-lane reduce
// groups never cross dst boundaries (LPD >= 8). Rows 4-padded in colx; pads
// hold node 0, killed by the -INF mask. Two-phase (A/B) step-4 loop with
// midpoint break: 2-buffer pipeline, no rotation moves, <=3 wasted slots.
template <int LOG_ROWB, int LPD_LOG, bool BF16_RELU_OUT>
__device__ __forceinline__ void agg_body(
    const int* __restrict__ rowptr, const int* __restrict__ deg,
    const int* __restrict__ colx, const int* __restrict__ order,
    const unsigned short* __restrict__ xs, const unsigned short* __restrict__ xd,
    const float* __restrict__ atts, const unsigned short* __restrict__ bias,
    void* __restrict__ hout, int N) {
  int lane = threadIdx.x & 63;
  int wid0 = __builtin_amdgcn_readfirstlane((int)((blockIdx.x * 256 + threadIdx.x) >> 6));
  int nWaves = (int)(gridDim.x << 2);
  constexpr int LPD = 1 << LPD_LOG;   // lanes per dst
  constexpr int DPW = 64 >> LPD_LOG;  // dsts per wave
  int g = lane >> LPD_LOG;
  int s = lane & (LPD - 1);
  unsigned int lb = (unsigned int)s * 16;  // byte offset within bf16 row
  int ch0 = s * 8;
  const char* xsb = (const char*)xs;
  floatx4 avl = *(const floatx4*)(atts + ch0);
  floatx4 avh = *(const floatx4*)(atts + ch0 + 4);
  float a0 = avl[0], a1 = avl[1], a2 = avl[2], a3 = avl[3];
  float a4 = avh[0], a5 = avh[1], a6 = avh[2], a7 = avh[3];
  float c0 = copysignf(C_ABS, a0), c1 = copysignf(C_ABS, a1);
  float c2 = copysignf(C_ABS, a2), c3 = copysignf(C_ABS, a3);
  float c4 = copysignf(C_ABS, a4), c5 = copysignf(C_ABS, a5);
  float c6 = copysignf(C_ABS, a6), c7 = copysignf(C_ABS, a7);
  int nGroups = (N + DPW - 1) / DPW;
  for (int grp = wid0; grp < nGroups; grp += nWaves) {
    int di = grp * DPW + g;
    bool valid = di < N;
    int dst = valid ? order[N - 1 - di] : 0;   // descending degree
    int beg = valid ? rowptr[dst] : 0;
    int lenv = valid ? deg[dst] + 1 : 0;
    uint4 du = *(const uint4*)((const char*)xd + ((size_t)dst << LOG_ROWB) + lb);
    float d0 = uasf(du.x << 16), d1 = uasf(du.x & 0xffff0000u);
    float d2 = uasf(du.y << 16), d3 = uasf(du.y & 0xffff0000u);
    float d4 = uasf(du.z << 16), d5 = uasf(du.z & 0xffff0000u);
    float d6 = uasf(du.w << 16), d7 = uasf(du.w & 0xffff0000u);
    float ad0 = a0 * d0, ad1 = a1 * d1, ad2 = a2 * d2, ad3 = a3 * d3;
    float ad4 = a4 * d4, ad5 = a5 * d5, ad6 = a6 * d6, ad7 = a7 * d7;
    float l = 0.f;
    float o0 = 0.f, o1 = 0.f, o2 = 0.f, o3 = 0.f;
    float o4 = 0.f, o5 = 0.f, o6 = 0.f, o7 = 0.f;
    const int* cx = colx + beg;
#define GATH(p) (*(const uint4*)(xsb + (((unsigned)(p) << LOG_ROWB) + lb)))
    intx4 qA = *(const intx4*)(cx);
    intx4 qB = *(const intx4*)(cx + 4);
    uint4 uA0 = GATH(qA.x), uA1 = GATH(qA.y), uA2 = GATH(qA.z), uA3 = GATH(qA.w);
    uint4 uB0 = GATH(qB.x), uB1 = GATH(qB.y), uB2 = GATH(qB.z), uB3 = GATH(qB.w);
    for (int e = 0;; e += 8) {
      intx4 qC = *(const intx4*)(cx + e + 8);
      int rem = lenv - e;
      AGG1(uA0, 0, rem) AGG1(uA1, 1, rem) AGG1(uA2, 2, rem) AGG1(uA3, 3, rem)
      uA0 = GATH(qC.x); uA1 = GATH(qC.y); uA2 = GATH(qC.z); uA3 = GATH(qC.w);
      if (rem <= 4) break;
      intx4 qD = *(const intx4*)(cx + e + 12);
      int rem4 = rem - 4;
      AGG1(uB0, 0, rem4) AGG1(uB1, 1, rem4) AGG1(uB2, 2, rem4) AGG1(uB3, 3, rem4)
      uB0 = GATH(qD.x); uB1 = GATH(qD.y); uB2 = GATH(qD.z); uB3 = GATH(qD.w);
      if (rem <= 8) break;
    }
#undef GATH
    if (valid) {
      float rl = 1.0f / l;
      uint4 bu = *(const uint4*)((const char*)bias + lb);
      float b0 = uasf(bu.x << 16), b1 = uasf(bu.x & 0xffff0000u);
      float b2 = uasf(bu.y << 16), b3 = uasf(bu.y & 0xffff0000u);
      float b4 = uasf(bu.z << 16), b5 = uasf(bu.z & 0xffff0000u);
      float b6 = uasf(bu.w << 16), b7 = uasf(bu.w & 0xffff0000u);
      float r0 = fmaf(o0, rl, b0), r1 = fmaf(o1, rl, b1);
      float r2 = fmaf(o2, rl, b2), r3 = fmaf(o3, rl, b3);
      float r4 = fmaf(o4, rl, b4), r5 = fmaf(o5, rl, b5);
      float r6 = fmaf(o6, rl, b6), r7 = fmaf(o7, rl, b7);
      if constexpr (BF16_RELU_OUT) {
        r0 = fmaxf(r0, 0.f); r1 = fmaxf(r1, 0.f); r2 = fmaxf(r2, 0.f); r3 = fmaxf(r3, 0.f);
        r4 = fmaxf(r4, 0.f); r5 = fmaxf(r5, 0.f); r6 = fmaxf(r6, 0.f); r7 = fmaxf(r7, 0.f);
        uint4 res;
        res.x = (unsigned)f2bf(r0) | ((unsigned)f2bf(r1) << 16);
        res.y = (unsigned)f2bf(r2) | ((unsigned)f2bf(r3) << 16);
        res.z = (unsigned)f2bf(r4) | ((unsigned)f2bf(r5) << 16);
        res.w = (unsigned)f2bf(r6) | ((unsigned)f2bf(r7) << 16);
        *(uint4*)((char*)hout + ((size_t)dst << LOG_ROWB) + lb) = res;
      } else {
        floatx4 ra = {r0, r1, r2, r3}, rb = {r4, r5, r6, r7};
        char* op = (char*)hout + (size_t)dst * 256 + (unsigned)ch0 * 4;
        *(floatx4*)op = ra;
        *(floatx4*)(op + 16) = rb;
      }
    }
  }
}

// layer-1: H=4 C=64 (row 512B), 32 lanes/dst (2 dst/wave), bf16+relu out
__global__ __launch_bounds__(256) void k_agg_h4(
    const int* __restrict__ rowptr, const int* __restrict__ deg,
    const int* __restrict__ colx, const int* __restrict__ order,
    const unsigned short* __restrict__ xs, const unsigned short* __restrict__ xd,
    const float* __restrict__ atts, const unsigned short* __restrict__ bias,
    unsigned short* __restrict__ hout, int N) {
  agg_body<9, 5, true>(rowptr, deg, colx, order, xs, xd, atts, bias, hout, N);
}

// layer-2: H=1 C=64 (row 128B), 8 lanes/dst (8 dst/wave), f32 out
__global__ __launch_bounds__(256) void k_agg_h1(
    const int* __restrict__ rowptr, const int* __restrict__ deg,
    const int* __restrict__ colx, const int* __restrict__ order,
    const unsigned short* __restrict__ xs, const unsigned short* __restrict__ xd,
    const float* __restrict__ atts, const unsigned short* __restrict__ bias,
    float* __restrict__ hout, int N) {
  agg_body<7, 3, false>(rowptr, deg, colx, order, xs, xd, atts, bias, hout, N);
}

// ---------------- mean pool over sorted batch [R8-measured] ----------------
__global__ __launch_bounds__(256) void k_pool(const float* __restrict__ h2,
                                              const int* __restrict__ batch,
                                              float* pool, int* cnt, int N) {
  int lane = threadIdx.x & 63;
  int wid = (blockIdx.x * 256 + threadIdx.x) >> 6;
  int n0 = wid * 32;
  if (n0 >= N) return;
  int nend = imin(n0 + 32, N);
  float acc = 0.f;
  int c = 0;
  int gcur = iclamp(batch[n0], 0, 63);
  for (int n = n0; n < nend; ++n) {
    int gg = iclamp(batch[n], 0, 63);
    if (gg != gcur) {
      atomicAdd(&pool[gcur * 64 + lane], acc);
      if (lane == 0) atomicAdd(&cnt[gcur], c);
      acc = 0.f; c = 0; gcur = gg;
    }
    acc += h2[(size_t)n * 64 + lane];
    c++;
  }
  atomicAdd(&pool[gcur * 64 + lane], acc);
  if (lane == 0) atomicAdd(&cnt[gcur], c);
}

// ---------------- final ----------------
__global__ void k_final(const float* __restrict__ pool, const int* __restrict__ cnt,
                        const unsigned short* __restrict__ Wlinc,
                        const unsigned short* __restrict__ blinc,
                        float* __restrict__ out) {
  int g = threadIdx.x;
  if (g >= 64) return;
  float inv = 1.f / fmaxf((float)cnt[g], 1.f);
  float s = 0.f;
  for (int c = 0; c < 64; ++c) s += pool[g * 64 + c] * bf2f(Wlinc[c]);
  out[g] = fmaf(s, inv, bf2f(blinc[0]));
}

extern "C" void kernel_launch(void* const* d_in, const int* in_sizes, int n_in,
                              void* d_out, int out_size, void* d_ws, size_t ws_size,
                              hipStream_t stream) {
  const void* x     = d_in[0];
  const int*  ei    = (const int*)d_in[1];
  const int*  batch = (const int*)d_in[2];
  const void* Wl1 = d_in[3];  const void* bl1 = d_in[4];
  const void* Wr1 = d_in[5];  const void* br1 = d_in[6];
  const void* att1 = d_in[7]; const void* bias1 = d_in[8];
  const void* Wl2 = d_in[9];  const void* bl2 = d_in[10];
  const void* Wr2 = d_in[11]; const void* br2 = d_in[12];
  const void* att2 = d_in[13]; const void* bias2 = d_in[14];
  const void* Wlin = d_in[15]; const void* blin = d_in[16];
  float* out = (float*)d_out;

  const int F = 128, HC = 256, C2 = 64;
  int N = in_sizes[0] / F;
  int E = in_sizes[1] / 2;
  int ET = E + N;
  const int* esrc = ei;
  const int* edst = ei + E;

  // ---- workspace carve-up ----
  char* w = (char*)d_ws;
  auto alloc = [&](size_t bytes) {
    char* p = w;
    w += (bytes + 255) & ~(size_t)255;
    return p;
  };
  int* dflag  = (int*)alloc(4);
  int* rowptr = (int*)alloc((size_t)(N + 1) * 4);
  int* cursor = (int*)alloc((size_t)N * 4);
  int* bsum   = (int*)alloc(1024 * 4);
  int* colx   = (int*)alloc((size_t)(E + 4 * N + 1024 + 16) * 4);  // 4-padded rows + tail
  int* order  = (int*)alloc((size_t)N * 4);
  unsigned short* smallc = (unsigned short*)alloc(4096);
  float* att1s = (float*)alloc(256 * 4);
  float* att2s = (float*)alloc(64 * 4);
  unsigned short* Wl1T = (unsigned short*)alloc((size_t)F * HC * 2);
  unsigned short* Wr1T = (unsigned short*)alloc((size_t)F * HC * 2);
  unsigned short* Wl2T = (unsigned short*)alloc((size_t)HC * C2 * 2);
  unsigned short* Wr2T = (unsigned short*)alloc((size_t)HC * C2 * 2);
  int* deg    = (int*)alloc((size_t)N * 4);     // zero-region start
  float* pool = (float*)alloc(64 * 64 * 4);
  int* cnt    = (int*)alloc(64 * 4);
  int* dhist  = (int*)alloc(256 * 4);
  int* dcur   = (int*)alloc(256 * 4);           // zero-region end
  unsigned short* xs1  = (unsigned short*)alloc((size_t)N * HC * 2);
  unsigned short* xd1  = (unsigned short*)alloc((size_t)N * HC * 2);
  unsigned short* h1   = (unsigned short*)alloc((size_t)N * HC * 2);
  size_t required = (size_t)(w - (char*)d_ws);
  size_t zlen = (size_t)((char*)dcur + 1024 - (char*)deg);

  unsigned short* x_c = h1;
  unsigned short* xs2 = xs1;
  unsigned short* xd2 = xs1 + (size_t)N * C2;
  float*          h2  = (float*)xd1;

  unsigned short* bl1c   = smallc + 0;
  unsigned short* br1c   = smallc + 256;
  unsigned short* att1c  = smallc + 512;
  unsigned short* bias1c = smallc + 768;
  unsigned short* bl2c   = smallc + 1024;
  unsigned short* br2c   = smallc + 1088;
  unsigned short* att2c  = smallc + 1152;
  unsigned short* bias2c = smallc + 1216;
  unsigned short* Wlinc  = smallc + 1280;
  unsigned short* blinc  = smallc + 1344;

  if (ws_size < required) {
    k_sentinel<<<1, 64, 0, stream>>>(out, 1000.f + (float)(ws_size >> 20));
    return;
  }

  hipMemsetAsync(deg, 0, zlen, stream);
  // zero the colx slice [E+N, E+4N+1024+16): covers the gap past rowptr[N]
  // (rowptr[N] >= E+N always) plus the prefetch-overrun tail.
  hipMemsetAsync(colx + (size_t)E + N, 0, ((size_t)3 * N + 1024 + 16) * 4, stream);

  // ---- mega prep: probe | cvt8 | small cvts | transposes | hist(4/thread) ----
  CvtSegs segs;
  const void* ssrc[10] = {bl1, br1, att1, bias1, bl2, br2, att2, bias2, Wlin, blin};
  unsigned short* sdst[10] = {bl1c, br1c, att1c, bias1c, bl2c, br2c, att2c, bias2c, Wlinc, blinc};
  int slen[10] = {256, 256, 256, 256, 64, 64, 64, 64, 64, 1};
  for (int i = 0; i < 10; ++i) { segs.src[i] = ssrc[i]; segs.dst[i] = sdst[i]; segs.len[i] = slen[i]; }
  int n8 = N * F / 8;
  int nCvt8 = (n8 + 255) / 256;
  int nTransB = (2 * F * HC + 2 * HC * C2 + 255) / 256;
  int nHist = (E + 1023) / 1024;
  k_prep<<<nCvt8 + 10 + nTransB + nHist, 256, 0, stream>>>(
      x, x_c, n8, segs, Wl1, Wr1, Wl2, Wr2, Wl1T, Wr1T, Wl2T, Wr2T,
      edst, deg, E, N, dflag, att1s, att2s, nCvt8, nTransB);

  // ---- scan (padded row capacities) + degree histogram/scan ----
  int nb = (N + 1023) / 1024;
  k_scan1<<<nb, 1024, 0, stream>>>(deg, bsum, dhist, N);
  k_scan3<<<nb, 1024, 0, stream>>>(deg, bsum, dhist, dcur, rowptr, cursor, N);

  // ---- phase1: interleaved layer-1 GEMM || scatter + degree-sort order ----
  int nG = ((N + 127) / 128) * 2;
  int nS = (ET + 1023) / 1024;
  k_phase1<<<nG + nS, 256, 0, stream>>>(
      (const unsigned short*)x, x_c, dflag, Wl1T, Wr1T, bl1c, br1c, xs1, xd1,
      N, HC, nG, nS, esrc, edst, rowptr, deg, cursor, colx, dcur, order, E, N);

  // ---- layer 1 aggregation: persistent strided waves, heavy-first ----
  k_agg_h4<<<2048, 256, 0, stream>>>(rowptr, deg, colx, order, xs1, xd1,
                                     att1s, bias1c, h1, N);

  // ---- layer 2 ----
  k_gemm2r_l2<<<(N + 63) / 64, 256, 0, stream>>>(h1, Wl2T, Wr2T, bl2c, br2c, xs2, xd2, N, C2);
  k_agg_h1<<<(N + 31) / 32, 256, 0, stream>>>(rowptr, deg, colx, order, xs2, xd2,
                                              att2s, bias2c, h2, N);

  // ---- pool + final ----
  int pw = (N + 31) / 32;
  k_pool<<<(pw + 3) / 4, 256, 0, stream>>>(h2, batch, pool, cnt, N);
  k_final<<<1, 64, 0, stream>>>(pool, cnt, Wlinc, blinc, out);
}

// Round 4
// 353.282 us; speedup vs baseline: 1.0161x; 1.0161x over previous
//
#include <hip/hip_runtime.h>
#include <hip/hip_bf16.h>
#include <math.h>

typedef __attribute__((ext_vector_type(8))) short short8;
typedef __attribute__((ext_vector_type(4))) float floatx4;
typedef __attribute__((ext_vector_type(4))) int intx4;

#define ATT_SCALE 0.865617024533378f  /* 0.6 * log2(e) */
#define C_ABS 0.6666666666667f        /* 0.4 / 0.6 */
#define PCLAMP 86.5f                  /* ~60 nats in log2 domain */

__device__ __forceinline__ float bf2f(unsigned short u) {
  union { unsigned int i; float f; } v; v.i = ((unsigned int)u) << 16; return v.f;
}
__device__ __forceinline__ unsigned short f2bf(float f) {
  union { float f; unsigned int u; } v; v.f = f;
  unsigned int r = (v.u + 0x7fffu + ((v.u >> 16) & 1u)) >> 16;
  return (unsigned short)r;
}
__device__ __forceinline__ int imin(int a, int b) { return a < b ? a : b; }
__device__ __forceinline__ int iclamp(int v, int lo, int hi) {
  return v < lo ? lo : (v > hi ? hi : v);
}
__device__ __forceinline__ float uasf(unsigned int u) {
  union { unsigned int i; float f; } v; v.i = u; return v.f;
}
__device__ __forceinline__ float exp2fast(float x) {
#if __has_builtin(__builtin_amdgcn_exp2f)
  return __builtin_amdgcn_exp2f(x);
#else
  return exp2f(x);
#endif
}
// 8-lane group sum, PURE VALU (no DS pipe on the critical path):
// xor1/xor2 via quad_perm DPP; xor4 via two bank-masked DPP row shifts that
// merge into x[l^4] (row_shl:4 -> banks 1,3; row_shr:4 -> banks 0,2).
__device__ __forceinline__ float sum8(float x) {
  union { float f; int i; } a, t;
  a.f = x;
  t.i = __builtin_amdgcn_update_dpp(0, a.i, 0xB1, 0xF, 0xF, true); a.f += t.f;  // xor1
  t.i = __builtin_amdgcn_update_dpp(0, a.i, 0x4E, 0xF, 0xF, true); a.f += t.f;  // xor2
  t.i = __builtin_amdgcn_update_dpp(0, a.i, 0x104, 0xF, 0xA, false);            // row_shl:4
  t.i = __builtin_amdgcn_update_dpp(t.i, a.i, 0x114, 0xF, 0x5, false);          // row_shr:4
  a.f += t.f;                                                                   // + x[l^4]
  return a.f;
}

// ---------------- sentinel: ws too small ----------------
__global__ void k_sentinel(float* out, float val) {
  if (threadIdx.x < 64) out[threadIdx.x] = val;
}

// ---------------- small-vector conversion segments ----------------
struct CvtSegs {
  const void* src[10];
  unsigned short* dst[10];
  int len[10];
};

// ---- mega prep: probe | cvt8 | small cvts | transposes | colx-zero | hist ---
__global__ void k_prep(const void* __restrict__ x, unsigned short* __restrict__ x_c,
                       int n8, CvtSegs segs,
                       const void* __restrict__ s0, const void* __restrict__ s1,
                       const void* __restrict__ s2, const void* __restrict__ s3,
                       unsigned short* __restrict__ d0, unsigned short* __restrict__ d1,
                       unsigned short* __restrict__ d2, unsigned short* __restrict__ d3,
                       const int* __restrict__ edst, int* deg, int E, int N,
                       int* dflag, float* __restrict__ att1s, float* __restrict__ att2s,
                       int* __restrict__ colx,
                       int nCvt8, int nTransB, int nZeroB) {
  __shared__ int csh;
  if (threadIdx.x == 0) csh = 0;
  __syncthreads();
  {
    unsigned short u = ((const unsigned short*)x)[threadIdx.x];
    int e = (u >> 7) & 0xFF;
    atomicAdd(&csh, (u == 0) || (e >= 100 && e <= 145));
  }
  __syncthreads();
  int isf = (csh < 240);

  int b = blockIdx.x;
  if (b < nCvt8) {
    if (!isf) return;                       // bf16 input: x used directly
    int i = b * 256 + threadIdx.x;
    if (i >= n8) return;
    const float* s = (const float*)x + (size_t)i * 8;
    ushort4 a, c;
    a.x = f2bf(s[0]); a.y = f2bf(s[1]); a.z = f2bf(s[2]); a.w = f2bf(s[3]);
    c.x = f2bf(s[4]); c.y = f2bf(s[5]); c.z = f2bf(s[6]); c.w = f2bf(s[7]);
    ((ushort4*)x_c)[i * 2] = a;
    ((ushort4*)x_c)[i * 2 + 1] = c;
    return;
  }
  b -= nCvt8;
  if (b < 10) {
    if (b == 0 && threadIdx.x == 0) dflag[0] = isf;
    int i = threadIdx.x;
    if (i < segs.len[b]) {
      float v = isf ? ((const float*)segs.src[b])[i]
                    : bf2f(((const unsigned short*)segs.src[b])[i]);
      segs.dst[b][i] = f2bf(v);
      // scaled f32 attention coefficients (exp2-domain scores)
      if (b == 2) att1s[i] = v * ATT_SCALE;
      if (b == 6) att2s[i] = v * ATT_SCALE;
    }
    return;
  }
  b -= 10;
  if (b < nTransB) {
    int idx = b * 256 + threadIdx.x;  // flat over 98304 elements
    const void* src; unsigned short* dst; int R, C, loc;
    if (idx < 32768)      { src = s0; dst = d0; R = 128; C = 256; loc = idx; }
    else if (idx < 65536) { src = s1; dst = d1; R = 128; C = 256; loc = idx - 32768; }
    else if (idx < 81920) { src = s2; dst = d2; R = 256; C = 64;  loc = idx - 65536; }
    else                  { src = s3; dst = d3; R = 256; C = 64;  loc = idx - 81920; }
    unsigned short u = isf ? f2bf(((const float*)src)[loc])
                           : ((const unsigned short*)src)[loc];
    int r = loc / C, cc = loc - r * C;
    dst[cc * R + r] = u;
    return;
  }
  b -= nTransB;
  if (b < nZeroB) {
    // zero colx slice [E+N, E+4N+1040): gap past rowptr[N] + prefetch tail
    int lim = (E + N) + 3 * N + 1024 + 16;
    int base = (E + N) + b * 1024 + threadIdx.x;
#pragma unroll
    for (int k = 0; k < 4; ++k) {
      int j = base + k * 256;
      if (j < lim) colx[j] = 0;
    }
    return;
  }
  b -= nZeroB;
  // histogram: 4 edges per thread (independent atomic chains) [R8-measured]
  int base = b * 1024 + threadIdx.x;
#pragma unroll
  for (int k = 0; k < 4; ++k) {
    int e = base + k * 256;
    if (e < E) atomicAdd(&deg[iclamp(edst[e], 0, N - 1)], 1);
  }
}

// ---------------- scan stage 1: per-1024 block sums + LDS-staged deg hist ----
// capacity = roundup4(deg + 1) so every CSR row starts 16B-aligned in colx.
__global__ __launch_bounds__(1024) void k_scan1(const int* __restrict__ deg, int* bsum,
                                                int* dhist, int N) {
  __shared__ int sm[1024];
  __shared__ int lh[256];
  int tid = threadIdx.x;
  if (tid < 256) lh[tid] = 0;
  __syncthreads();
  int i = blockIdx.x * 1024 + tid;
  int d = (i < N) ? deg[i] : 0;
  if (i < N) atomicAdd(&lh[imin(d, 255)], 1);
  sm[tid] = (i < N) ? ((d + 4) & ~3) : 0;
  __syncthreads();
  for (int off = 512; off > 0; off >>= 1) {
    if (tid < off) sm[tid] += sm[tid + off];
    __syncthreads();
  }
  if (tid == 0) bsum[blockIdx.x] = sm[0];
  if (tid < 256 && lh[tid]) atomicAdd(&dhist[tid], lh[tid]);
}

// ---- scan stage 2: Hillis-Steele + inline bsum prefix -> rowptr & cursor ----
// Block 0 additionally exclusive-scans the 256-bin degree histogram -> dcur.
__global__ __launch_bounds__(1024) void k_scan3(const int* __restrict__ deg,
                                                const int* __restrict__ bsum,
                                                const int* __restrict__ dhist,
                                                int* dcur,
                                                int* rowptr, int* cursor, int N) {
  __shared__ int sm[1024];
  __shared__ int boff;
  __shared__ int hsc[256];
  int tid = threadIdx.x;
  if (tid == 0) {
    int r = 0;
    for (int b = 0; b < blockIdx.x; ++b) r += bsum[b];
    boff = r;
  }
  int i = blockIdx.x * 1024 + tid;
  int v = (i < N) ? ((deg[i] + 4) & ~3) : 0;
  sm[tid] = v;
  __syncthreads();
  for (int off = 1; off < 1024; off <<= 1) {
    int t = (tid >= off) ? sm[tid - off] : 0;
    __syncthreads();
    sm[tid] += t;
    __syncthreads();
  }
  if (i < N) {
    int ex = sm[tid] - v + boff;
    rowptr[i] = ex;
    cursor[i] = ex;
    if (i == N - 1) rowptr[N] = ex + v;
  }
  // ---- block 0: exclusive scan of dhist into dcur ----
  int hv = 0;
  if (blockIdx.x == 0 && tid < 256) { hv = dhist[tid]; hsc[tid] = hv; }
  __syncthreads();
  for (int off = 1; off < 256; off <<= 1) {
    int t = 0;
    if (blockIdx.x == 0 && tid < 256 && tid >= off) t = hsc[tid - off];
    __syncthreads();
    if (blockIdx.x == 0 && tid < 256) hsc[tid] += t;
    __syncthreads();
  }
  if (blockIdx.x == 0 && tid < 256) dcur[tid] = hsc[tid] - hv;
}

// ------ dual GEMM body, register-resident B + row loop (PF=1) ------
template <int K, int CT, int RT>
__device__ __forceinline__ void gemm2r_body(
    int bx, int by, int tid,
    const unsigned short* __restrict__ A,
    const unsigned short* __restrict__ BTl, const unsigned short* __restrict__ BTr,
    const unsigned short* __restrict__ bl, const unsigned short* __restrict__ br,
    unsigned short* __restrict__ outl, unsigned short* __restrict__ outr,
    int Nrows, int M) {
  constexpr int KI = K / 32;
  int lane = tid & 63;
  int wave = tid >> 6;
  int r = lane & 15, q = lane >> 4;
  int col0 = by * (4 * CT * 16) + wave * (CT * 16);
  int row0 = bx * (16 * RT);
  short8 Bl[KI][CT], Br[KI][CT];
#pragma unroll
  for (int t = 0; t < CT; ++t) {
    const unsigned short* bpl = BTl + (size_t)(col0 + t * 16 + r) * K + q * 8;
    const unsigned short* bpr = BTr + (size_t)(col0 + t * 16 + r) * K + q * 8;
#pragma unroll
    for (int k = 0; k < KI; ++k) {
      Bl[k][t] = *reinterpret_cast<const short8*>(bpl + k * 32);
      Br[k][t] = *reinterpret_cast<const short8*>(bpr + k * 32);
    }
  }
  float bvl[CT], bvr[CT];
#pragma unroll
  for (int t = 0; t < CT; ++t) {
    bvl[t] = bf2f(bl[col0 + t * 16 + r]);
    bvr[t] = bf2f(br[col0 + t * 16 + r]);
  }
  short8 a[KI], an[KI];
  {
    int ar0 = imin(row0 + r, Nrows - 1);
    const unsigned short* Ap = A + (size_t)ar0 * K + q * 8;
#pragma unroll
    for (int k = 0; k < KI; ++k) a[k] = *reinterpret_cast<const short8*>(Ap + k * 32);
  }
  for (int rt = 0; rt < RT; ++rt) {
    if (rt + 1 < RT) {
      int arn = imin(row0 + (rt + 1) * 16 + r, Nrows - 1);
      const unsigned short* Apn = A + (size_t)arn * K + q * 8;
#pragma unroll
      for (int k = 0; k < KI; ++k) an[k] = *reinterpret_cast<const short8*>(Apn + k * 32);
    }
    floatx4 accl[CT], accr[CT];
#pragma unroll
    for (int t = 0; t < CT; ++t) {
      accl[t] = (floatx4){0.f, 0.f, 0.f, 0.f};
      accr[t] = (floatx4){0.f, 0.f, 0.f, 0.f};
    }
#pragma unroll
    for (int k = 0; k < KI; ++k) {
#pragma unroll
      for (int t = 0; t < CT; ++t) {
        accl[t] = __builtin_amdgcn_mfma_f32_16x16x32_bf16(a[k], Bl[k][t], accl[t], 0, 0, 0);
        accr[t] = __builtin_amdgcn_mfma_f32_16x16x32_bf16(a[k], Br[k][t], accr[t], 0, 0, 0);
      }
    }
#pragma unroll
    for (int t = 0; t < CT; ++t) {
      int col = col0 + t * 16 + r;
#pragma unroll
      for (int rr = 0; rr < 4; ++rr) {
        int row = row0 + rt * 16 + q * 4 + rr;
        if (row < Nrows) {
          outl[(size_t)row * M + col] = f2bf(accl[t][rr] + bvl[t]);
          outr[(size_t)row * M + col] = f2bf(accr[t][rr] + bvr[t]);
        }
      }
    }
#pragma unroll
    for (int k = 0; k < KI; ++k) a[k] = an[k];
  }
}

// ------ phase1: INTERLEAVED layer-1 GEMM || scatter (role by block parity) ----
// Scatter blocks also do the degree-bucketed node ordering (LDS-staged counting
// sort scatter) and CSR pad-fill.
__global__ __launch_bounds__(256) void k_phase1(
    const unsigned short* __restrict__ A0, const unsigned short* __restrict__ A1,
    const int* __restrict__ dflag,
    const unsigned short* __restrict__ BTl, const unsigned short* __restrict__ BTr,
    const unsigned short* __restrict__ bl, const unsigned short* __restrict__ br,
    unsigned short* __restrict__ outl, unsigned short* __restrict__ outr,
    int Nrows, int M, int nG, int nS,
    const int* __restrict__ esrc, const int* __restrict__ edst,
    const int* __restrict__ rowptr, const int* __restrict__ deg,
    int* cursor, int* colx, int* dcur, int* order, int E, int N) {
  int b = blockIdx.x;
  int m2 = 2 * imin(nG, nS);
  bool isG;
  int idx;
  if (b < m2) { isG = (b & 1) == 0; idx = b >> 1; }
  else        { isG = nG > nS;      idx = imin(nG, nS) + (b - m2); }
  if (isG) {
    const unsigned short* A = dflag[0] ? A1 : A0;
    gemm2r_body<128, 2, 8>(idx >> 1, idx & 1, threadIdx.x, A, BTl, BTr, bl, br,
                           outl, outr, Nrows, M);
    return;
  }
  // ---- scatter role ----
  __shared__ int scnt[256];
  __shared__ int sbase[256];
  int ET = E + N;
  int ETcap = E + 4 * N;
  int base = idx * 1024 + threadIdx.x;
  if (threadIdx.x < 256) scnt[threadIdx.x] = 0;
  __syncthreads();
  // edges: 4 per thread (independent atomic chains)
#pragma unroll
  for (int k = 0; k < 4; ++k) {
    int e = base + k * 256;
    if (e < E) {
      int s = iclamp(esrc[e], 0, N - 1), d = iclamp(edst[e], 0, N - 1);
      int pos = atomicAdd(&cursor[d], 1);
      colx[iclamp(pos, 0, ETcap - 1)] = s;
    }
  }
  // nodes: self-loop slot + pad fill + degree-bin local index (static slots)
  bool n0 = false, n1 = false, n2 = false, n3 = false;
  int i0 = 0, i1 = 0, i2 = 0, i3 = 0, b0 = 0, b1 = 0, b2 = 0, b3 = 0;
  int l0 = 0, l1 = 0, l2 = 0, l3 = 0;
#define NODEK(nk, ik, bk, lk, KK) { int e = base + KK * 256;                  \
    if (e >= E && e < ET) { int i = e - E; int bg = rowptr[i]; int dv = deg[i]; \
      colx[bg + dv] = i; int cap = rowptr[i + 1];                             \
      for (int j = bg + dv + 1; j < cap; ++j) colx[j] = 0;                    \
      ik = i; bk = imin(dv, 255); lk = atomicAdd(&scnt[bk], 1); nk = true; } }
  NODEK(n0, i0, b0, l0, 0) NODEK(n1, i1, b1, l1, 1)
  NODEK(n2, i2, b2, l2, 2) NODEK(n3, i3, b3, l3, 3)
#undef NODEK
  __syncthreads();
  if (threadIdx.x < 256 && scnt[threadIdx.x])
    sbase[threadIdx.x] = atomicAdd(&dcur[threadIdx.x], scnt[threadIdx.x]);
  __syncthreads();
  if (n0) order[sbase[b0] + l0] = i0;
  if (n1) order[sbase[b1] + l1] = i1;
  if (n2) order[sbase[b2] + l2] = i2;
  if (n3) order[sbase[b3] + l3] = i3;
}

// ---------------- layer-2 GEMM ----------------
__global__ __launch_bounds__(256) void k_gemm2r_l2(
    const unsigned short* __restrict__ A,
    const unsigned short* __restrict__ BTl, const unsigned short* __restrict__ BTr,
    const unsigned short* __restrict__ bl, const unsigned short* __restrict__ br,
    unsigned short* __restrict__ outl, unsigned short* __restrict__ outr,
    int Nrows, int M) {
  gemm2r_body<256, 1, 4>(blockIdx.x, 0, threadIdx.x, A, BTl, BTr, bl, br,
                         outl, outr, Nrows, M);
}

// One edge-slot: unpack 8 bf16 -> q=fma(a,v,ad) -> score p (exp2 domain) ->
// 8-lane reduce -> masked exp2 -> accumulate l, o0..o7.
#define AGG1(U, KK, REM)                                                     \
  {                                                                          \
    float v0 = uasf(U.x << 16), v1 = uasf(U.x & 0xffff0000u);                \
    float v2 = uasf(U.y << 16), v3 = uasf(U.y & 0xffff0000u);                \
    float v4 = uasf(U.z << 16), v5 = uasf(U.z & 0xffff0000u);                \
    float v6 = uasf(U.w << 16), v7 = uasf(U.w & 0xffff0000u);                \
    float q0 = fmaf(a0, v0, ad0), q1 = fmaf(a1, v1, ad1);                    \
    float q2 = fmaf(a2, v2, ad2), q3 = fmaf(a3, v3, ad3);                    \
    float q4 = fmaf(a4, v4, ad4), q5 = fmaf(a5, v5, ad5);                    \
    float q6 = fmaf(a6, v6, ad6), q7 = fmaf(a7, v7, ad7);                    \
    float p = ((q0 + q1) + (q2 + q3)) + ((q4 + q5) + (q6 + q7));             \
    p = fmaf(c0, fabsf(q0), p); p = fmaf(c1, fabsf(q1), p);                  \
    p = fmaf(c2, fabsf(q2), p); p = fmaf(c3, fabsf(q3), p);                  \
    p = fmaf(c4, fabsf(q4), p); p = fmaf(c5, fabsf(q5), p);                  \
    p = fmaf(c6, fabsf(q6), p); p = fmaf(c7, fabsf(q7), p);                  \
    p = sum8(p);                                                             \
    float lim = (KK < (REM)) ? PCLAMP : -INFINITY;                           \
    p = fminf(p, lim);                                                       \
    float w = exp2fast(p);                                                   \
    l += w;                                                                  \
    o0 = fmaf(w, v0, o0); o1 = fmaf(w, v1, o1);                              \
    o2 = fmaf(w, v2, o2); o3 = fmaf(w, v3, o3);                              \
    o4 = fmaf(w, v4, o4); o5 = fmaf(w, v5, o5);                              \
    o6 = fmaf(w, v6, o6); o7 = fmaf(w, v7, o7);                              \
  }

// ------- unified aggregation body: LPD lanes per dst, 8 channels per lane ----
// Exact dispatch: ONE dst-group per wave, walked in DESCENDING degree order
// (order[] ascending, indexed reversed): heavy rows dispatch first, light rows
// drain the tail; the DPW dsts sharing a wave are sorted-adjacent so lengths
// match (near-zero divergence). 8-lane reduce groups never cross dst
// boundaries (LPD >= 8). Rows 4-padded in colx; pads hold node 0, killed by
// the -INF mask. Two-phase (A/B) step-4 loop with midpoint break: 2-buffer
// pipeline, no rotation moves, <=3 wasted slots.
template <int LOG_ROWB, int LPD_LOG, bool BF16_RELU_OUT>
__device__ __forceinline__ void agg_body(
    const int* __restrict__ rowptr, const int* __restrict__ deg,
    const int* __restrict__ colx, const int* __restrict__ order,
    const unsigned short* __restrict__ xs, const unsigned short* __restrict__ xd,
    const float* __restrict__ atts, const unsigned short* __restrict__ bias,
    void* __restrict__ hout, int N) {
  int lane = threadIdx.x & 63;
  int wid = (blockIdx.x * 256 + threadIdx.x) >> 6;
  constexpr int LPD = 1 << LPD_LOG;   // lanes per dst
  constexpr int DPW = 64 >> LPD_LOG;  // dsts per wave
  int g = lane >> LPD_LOG;
  int s = lane & (LPD - 1);
  int di = wid * DPW + g;
  bool valid = di < N;
  int dst = valid ? order[N - 1 - di] : 0;   // descending degree
  int beg = valid ? rowptr[dst] : 0;
  int lenv = valid ? deg[dst] + 1 : 0;
  unsigned int lb = (unsigned int)s * 16;  // byte offset within bf16 row
  int ch0 = s * 8;
  const char* xsb = (const char*)xs;
  floatx4 avl = *(const floatx4*)(atts + ch0);
  floatx4 avh = *(const floatx4*)(atts + ch0 + 4);
  float a0 = avl[0], a1 = avl[1], a2 = avl[2], a3 = avl[3];
  float a4 = avh[0], a5 = avh[1], a6 = avh[2], a7 = avh[3];
  float c0 = copysignf(C_ABS, a0), c1 = copysignf(C_ABS, a1);
  float c2 = copysignf(C_ABS, a2), c3 = copysignf(C_ABS, a3);
  float c4 = copysignf(C_ABS, a4), c5 = copysignf(C_ABS, a5);
  float c6 = copysignf(C_ABS, a6), c7 = copysignf(C_ABS, a7);
  uint4 du = *(const uint4*)((const char*)xd + ((size_t)dst << LOG_ROWB) + lb);
  float d0 = uasf(du.x << 16), d1 = uasf(du.x & 0xffff0000u);
  float d2 = uasf(du.y << 16), d3 = uasf(du.y & 0xffff0000u);
  float d4 = uasf(du.z << 16), d5 = uasf(du.z & 0xffff0000u);
  float d6 = uasf(du.w << 16), d7 = uasf(du.w & 0xffff0000u);
  float ad0 = a0 * d0, ad1 = a1 * d1, ad2 = a2 * d2, ad3 = a3 * d3;
  float ad4 = a4 * d4, ad5 = a5 * d5, ad6 = a6 * d6, ad7 = a7 * d7;
  float l = 0.f;
  float o0 = 0.f, o1 = 0.f, o2 = 0.f, o3 = 0.f;
  float o4 = 0.f, o5 = 0.f, o6 = 0.f, o7 = 0.f;
  const int* cx = colx + beg;
#define GATH(p) (*(const uint4*)(xsb + (((unsigned)(p) << LOG_ROWB) + lb)))
  intx4 qA = *(const intx4*)(cx);
  intx4 qB = *(const intx4*)(cx + 4);
  uint4 uA0 = GATH(qA.x), uA1 = GATH(qA.y), uA2 = GATH(qA.z), uA3 = GATH(qA.w);
  uint4 uB0 = GATH(qB.x), uB1 = GATH(qB.y), uB2 = GATH(qB.z), uB3 = GATH(qB.w);
  for (int e = 0;; e += 8) {
    intx4 qC = *(const intx4*)(cx + e + 8);
    int rem = lenv - e;
    AGG1(uA0, 0, rem) AGG1(uA1, 1, rem) AGG1(uA2, 2, rem) AGG1(uA3, 3, rem)
    uA0 = GATH(qC.x); uA1 = GATH(qC.y); uA2 = GATH(qC.z); uA3 = GATH(qC.w);
    if (rem <= 4) break;
    intx4 qD = *(const intx4*)(cx + e + 12);
    int rem4 = rem - 4;
    AGG1(uB0, 0, rem4) AGG1(uB1, 1, rem4) AGG1(uB2, 2, rem4) AGG1(uB3, 3, rem4)
    uB0 = GATH(qD.x); uB1 = GATH(qD.y); uB2 = GATH(qD.z); uB3 = GATH(qD.w);
    if (rem <= 8) break;
  }
#undef GATH
  if (!valid) return;
  float rl = 1.0f / l;
  uint4 bu = *(const uint4*)((const char*)bias + lb);
  float b0 = uasf(bu.x << 16), b1 = uasf(bu.x & 0xffff0000u);
  float b2 = uasf(bu.y << 16), b3 = uasf(bu.y & 0xffff0000u);
  float b4 = uasf(bu.z << 16), b5 = uasf(bu.z & 0xffff0000u);
  float b6 = uasf(bu.w << 16), b7 = uasf(bu.w & 0xffff0000u);
  float r0 = fmaf(o0, rl, b0), r1 = fmaf(o1, rl, b1);
  float r2 = fmaf(o2, rl, b2), r3 = fmaf(o3, rl, b3);
  float r4 = fmaf(o4, rl, b4), r5 = fmaf(o5, rl, b5);
  float r6 = fmaf(o6, rl, b6), r7 = fmaf(o7, rl, b7);
  if constexpr (BF16_RELU_OUT) {
    r0 = fmaxf(r0, 0.f); r1 = fmaxf(r1, 0.f); r2 = fmaxf(r2, 0.f); r3 = fmaxf(r3, 0.f);
    r4 = fmaxf(r4, 0.f); r5 = fmaxf(r5, 0.f); r6 = fmaxf(r6, 0.f); r7 = fmaxf(r7, 0.f);
    uint4 res;
    res.x = (unsigned)f2bf(r0) | ((unsigned)f2bf(r1) << 16);
    res.y = (unsigned)f2bf(r2) | ((unsigned)f2bf(r3) << 16);
    res.z = (unsigned)f2bf(r4) | ((unsigned)f2bf(r5) << 16);
    res.w = (unsigned)f2bf(r6) | ((unsigned)f2bf(r7) << 16);
    *(uint4*)((char*)hout + ((size_t)dst << LOG_ROWB) + lb) = res;
  } else {
    floatx4 ra = {r0, r1, r2, r3}, rb = {r4, r5, r6, r7};
    char* op = (char*)hout + (size_t)dst * 256 + (unsigned)ch0 * 4;
    *(floatx4*)op = ra;
    *(floatx4*)(op + 16) = rb;
  }
}

// layer-1: H=4 C=64 (row 512B), 32 lanes/dst (2 dst/wave), bf16+relu out
__global__ __launch_bounds__(256) void k_agg_h4(
    const int* __restrict__ rowptr, const int* __restrict__ deg,
    const int* __restrict__ colx, const int* __restrict__ order,
    const unsigned short* __restrict__ xs, const unsigned short* __restrict__ xd,
    const float* __restrict__ atts, const unsigned short* __restrict__ bias,
    unsigned short* __restrict__ hout, int N) {
  agg_body<9, 5, true>(rowptr, deg, colx, order, xs, xd, atts, bias, hout, N);
}

// layer-2: H=1 C=64 (row 128B), 8 lanes/dst (8 dst/wave), f32 out
__global__ __launch_bounds__(256) void k_agg_h1(
    const int* __restrict__ rowptr, const int* __restrict__ deg,
    const int* __restrict__ colx, const int* __restrict__ order,
    const unsigned short* __restrict__ xs, const unsigned short* __restrict__ xd,
    const float* __restrict__ atts, const unsigned short* __restrict__ bias,
    float* __restrict__ hout, int N) {
  agg_body<7, 3, false>(rowptr, deg, colx, order, xs, xd, atts, bias, hout, N);
}

// ---------------- mean pool over sorted batch [R8-measured] ----------------
__global__ __launch_bounds__(256) void k_pool(const float* __restrict__ h2,
                                              const int* __restrict__ batch,
                                              float* pool, int* cnt, int N) {
  int lane = threadIdx.x & 63;
  int wid = (blockIdx.x * 256 + threadIdx.x) >> 6;
  int n0 = wid * 32;
  if (n0 >= N) return;
  int nend = imin(n0 + 32, N);
  float acc = 0.f;
  int c = 0;
  int gcur = iclamp(batch[n0], 0, 63);
  for (int n = n0; n < nend; ++n) {
    int gg = iclamp(batch[n], 0, 63);
    if (gg != gcur) {
      atomicAdd(&pool[gcur * 64 + lane], acc);
      if (lane == 0) atomicAdd(&cnt[gcur], c);
      acc = 0.f; c = 0; gcur = gg;
    }
    acc += h2[(size_t)n * 64 + lane];
    c++;
  }
  atomicAdd(&pool[gcur * 64 + lane], acc);
  if (lane == 0) atomicAdd(&cnt[gcur], c);
}

// ---------------- final ----------------
__global__ void k_final(const float* __restrict__ pool, const int* __restrict__ cnt,
                        const unsigned short* __restrict__ Wlinc,
                        const unsigned short* __restrict__ blinc,
                        float* __restrict__ out) {
  int g = threadIdx.x;
  if (g >= 64) return;
  float inv = 1.f / fmaxf((float)cnt[g], 1.f);
  float s = 0.f;
  for (int c = 0; c < 64; ++c) s += pool[g * 64 + c] * bf2f(Wlinc[c]);
  out[g] = fmaf(s, inv, bf2f(blinc[0]));
}

extern "C" void kernel_launch(void* const* d_in, const int* in_sizes, int n_in,
                              void* d_out, int out_size, void* d_ws, size_t ws_size,
                              hipStream_t stream) {
  const void* x     = d_in[0];
  const int*  ei    = (const int*)d_in[1];
  const int*  batch = (const int*)d_in[2];
  const void* Wl1 = d_in[3];  const void* bl1 = d_in[4];
  const void* Wr1 = d_in[5];  const void* br1 = d_in[6];
  const void* att1 = d_in[7]; const void* bias1 = d_in[8];
  const void* Wl2 = d_in[9];  const void* bl2 = d_in[10];
  const void* Wr2 = d_in[11]; const void* br2 = d_in[12];
  const void* att2 = d_in[13]; const void* bias2 = d_in[14];
  const void* Wlin = d_in[15]; const void* blin = d_in[16];
  float* out = (float*)d_out;

  const int F = 128, HC = 256, C2 = 64;
  int N = in_sizes[0] / F;
  int E = in_sizes[1] / 2;
  int ET = E + N;
  const int* esrc = ei;
  const int* edst = ei + E;

  // ---- workspace carve-up ----
  char* w = (char*)d_ws;
  auto alloc = [&](size_t bytes) {
    char* p = w;
    w += (bytes + 255) & ~(size_t)255;
    return p;
  };
  int* dflag  = (int*)alloc(4);
  int* rowptr = (int*)alloc((size_t)(N + 1) * 4);
  int* cursor = (int*)alloc((size_t)N * 4);
  int* bsum   = (int*)alloc(1024 * 4);
  int* colx   = (int*)alloc((size_t)(E + 4 * N + 1024 + 16) * 4);  // 4-padded rows + tail
  int* order  = (int*)alloc((size_t)N * 4);
  unsigned short* smallc = (unsigned short*)alloc(4096);
  float* att1s = (float*)alloc(256 * 4);
  float* att2s = (float*)alloc(64 * 4);
  unsigned short* Wl1T = (unsigned short*)alloc((size_t)F * HC * 2);
  unsigned short* Wr1T = (unsigned short*)alloc((size_t)F * HC * 2);
  unsigned short* Wl2T = (unsigned short*)alloc((size_t)HC * C2 * 2);
  unsigned short* Wr2T = (unsigned short*)alloc((size_t)HC * C2 * 2);
  int* deg    = (int*)alloc((size_t)N * 4);     // zero-region start
  float* pool = (float*)alloc(64 * 64 * 4);
  int* cnt    = (int*)alloc(64 * 4);
  int* dhist  = (int*)alloc(256 * 4);
  int* dcur   = (int*)alloc(256 * 4);           // zero-region end
  unsigned short* xs1  = (unsigned short*)alloc((size_t)N * HC * 2);
  unsigned short* xd1  = (unsigned short*)alloc((size_t)N * HC * 2);
  unsigned short* h1   = (unsigned short*)alloc((size_t)N * HC * 2);
  size_t required = (size_t)(w - (char*)d_ws);
  size_t zlen = (size_t)((char*)dcur + 1024 - (char*)deg);

  unsigned short* x_c = h1;
  unsigned short* xs2 = xs1;
  unsigned short* xd2 = xs1 + (size_t)N * C2;
  float*          h2  = (float*)xd1;

  unsigned short* bl1c   = smallc + 0;
  unsigned short* br1c   = smallc + 256;
  unsigned short* att1c  = smallc + 512;
  unsigned short* bias1c = smallc + 768;
  unsigned short* bl2c   = smallc + 1024;
  unsigned short* br2c   = smallc + 1088;
  unsigned short* att2c  = smallc + 1152;
  unsigned short* bias2c = smallc + 1216;
  unsigned short* Wlinc  = smallc + 1280;
  unsigned short* blinc  = smallc + 1344;

  if (ws_size < required) {
    k_sentinel<<<1, 64, 0, stream>>>(out, 1000.f + (float)(ws_size >> 20));
    return;
  }

  hipMemsetAsync(deg, 0, zlen, stream);

  // ---- mega prep: probe | cvt8 | small | trans | colx-zero | hist ----
  CvtSegs segs;
  const void* ssrc[10] = {bl1, br1, att1, bias1, bl2, br2, att2, bias2, Wlin, blin};
  unsigned short* sdst[10] = {bl1c, br1c, att1c, bias1c, bl2c, br2c, att2c, bias2c, Wlinc, blinc};
  int slen[10] = {256, 256, 256, 256, 64, 64, 64, 64, 64, 1};
  for (int i = 0; i < 10; ++i) { segs.src[i] = ssrc[i]; segs.dst[i] = sdst[i]; segs.len[i] = slen[i]; }
  int n8 = N * F / 8;
  int nCvt8 = (n8 + 255) / 256;
  int nTransB = (2 * F * HC + 2 * HC * C2 + 255) / 256;
  int nZeroB = (3 * N + 1024 + 16 + 1023) / 1024;
  int nHist = (E + 1023) / 1024;
  k_prep<<<nCvt8 + 10 + nTransB + nZeroB + nHist, 256, 0, stream>>>(
      x, x_c, n8, segs, Wl1, Wr1, Wl2, Wr2, Wl1T, Wr1T, Wl2T, Wr2T,
      edst, deg, E, N, dflag, att1s, att2s, colx, nCvt8, nTransB, nZeroB);

  // ---- scan (padded row capacities) + degree histogram/scan ----
  int nb = (N + 1023) / 1024;
  k_scan1<<<nb, 1024, 0, stream>>>(deg, bsum, dhist, N);
  k_scan3<<<nb, 1024, 0, stream>>>(deg, bsum, dhist, dcur, rowptr, cursor, N);

  // ---- phase1: interleaved layer-1 GEMM || scatter + degree-sort order ----
  int nG = ((N + 127) / 128) * 2;
  int nS = (ET + 1023) / 1024;
  k_phase1<<<nG + nS, 256, 0, stream>>>(
      (const unsigned short*)x, x_c, dflag, Wl1T, Wr1T, bl1c, br1c, xs1, xd1,
      N, HC, nG, nS, esrc, edst, rowptr, deg, cursor, colx, dcur, order, E, N);

  // ---- layer 1 aggregation: 2 dst/wave, descending degree, exact grid ----
  int ng4 = (N + 1) / 2;
  k_agg_h4<<<(ng4 + 3) / 4, 256, 0, stream>>>(rowptr, deg, colx, order, xs1, xd1,
                                              att1s, bias1c, h1, N);

  // ---- layer 2 ----
  k_gemm2r_l2<<<(N + 63) / 64, 256, 0, stream>>>(h1, Wl2T, Wr2T, bl2c, br2c, xs2, xd2, N, C2);
  int ng1 = (N + 7) / 8;
  k_agg_h1<<<(ng1 + 3) / 4, 256, 0, stream>>>(rowptr, deg, colx, order, xs2, xd2,
                                              att2s, bias2c, h2, N);

  // ---- pool + final ----
  int pw = (N + 31) / 32;
  k_pool<<<(pw + 3) / 4, 256, 0, stream>>>(h2, batch, pool, cnt, N);
  k_final<<<1, 64, 0, stream>>>(pool, cnt, Wlinc, blinc, out);
}

// Round 6
// 334.051 us; speedup vs baseline: 1.0746x; 1.0576x over previous
//
#include <hip/hip_runtime.h>
#include <hip/hip_bf16.h>
#include <math.h>

typedef __attribute__((ext_vector_type(8))) short short8;
typedef __attribute__((ext_vector_type(4))) float floatx4;
typedef __attribute__((ext_vector_type(2))) float f32x2;

#define ATT_SCALE 0.865617024533378f  /* 0.6 * log2(e) */
#define C_ABS 0.6666666666667f        /* 0.4 / 0.6 */
#define PCLAMP 86.5f                  /* ~60 nats in log2 domain */

__device__ __forceinline__ float bf2f(unsigned short u) {
  union { unsigned int i; float f; } v; v.i = ((unsigned int)u) << 16; return v.f;
}
__device__ __forceinline__ unsigned short f2bf(float f) {
  union { float f; unsigned int u; } v; v.f = f;
  unsigned int r = (v.u + 0x7fffu + ((v.u >> 16) & 1u)) >> 16;
  return (unsigned short)r;
}
__device__ __forceinline__ int imin(int a, int b) { return a < b ? a : b; }
__device__ __forceinline__ int iclamp(int v, int lo, int hi) {
  return v < lo ? lo : (v > hi ? hi : v);
}
__device__ __forceinline__ float uasf(unsigned int u) {
  union { unsigned int i; float f; } v; v.i = u; return v.f;
}
__device__ __forceinline__ float exp2fast(float x) {
#if __has_builtin(__builtin_amdgcn_exp2f)
  return __builtin_amdgcn_exp2f(x);
#else
  return exp2f(x);
#endif
}
// elementwise |v| for f32x2 (pk_max(v,-v) when the builtin exists)
__device__ __forceinline__ f32x2 absv2(f32x2 v) {
#if __has_builtin(__builtin_elementwise_max)
  return __builtin_elementwise_max(v, -v);
#else
  f32x2 r; r[0] = fabsf(v[0]); r[1] = fabsf(v[1]); return r;
#endif
}
// 16-lane ring-rotation sum via DPP (pure VALU)
__device__ __forceinline__ float sum16(float x) {
  union { float f; int i; } a, t;
  a.f = x;
  t.i = __builtin_amdgcn_update_dpp(0, a.i, 0x121, 0xF, 0xF, true); a.f += t.f;
  t.i = __builtin_amdgcn_update_dpp(0, a.i, 0x122, 0xF, 0xF, true); a.f += t.f;
  t.i = __builtin_amdgcn_update_dpp(0, a.i, 0x124, 0xF, 0xF, true); a.f += t.f;
  t.i = __builtin_amdgcn_update_dpp(0, a.i, 0x128, 0xF, 0xF, true); a.f += t.f;
  return a.f;
}

// ---------------- sentinel: ws too small ----------------
__global__ void k_sentinel(float* out, float val) {
  if (threadIdx.x < 64) out[threadIdx.x] = val;
}

// ---------------- small-vector conversion segments ----------------
struct CvtSegs {
  const void* src[10];
  unsigned short* dst[10];
  int len[10];
};

// ---- mega prep: per-block dtype probe, then cvt8 | cvt_small | trans | hist --
__global__ void k_prep(const void* __restrict__ x, unsigned short* __restrict__ x_c,
                       int n8, CvtSegs segs,
                       const void* __restrict__ s0, const void* __restrict__ s1,
                       const void* __restrict__ s2, const void* __restrict__ s3,
                       unsigned short* __restrict__ d0, unsigned short* __restrict__ d1,
                       unsigned short* __restrict__ d2, unsigned short* __restrict__ d3,
                       const int* __restrict__ edst, int* deg, int E, int N,
                       int* dflag, int* colx, int ET,
                       float* __restrict__ att1s, float* __restrict__ att2s,
                       int nCvt8, int nTransB) {
  __shared__ int csh;
  if (threadIdx.x == 0) csh = 0;
  __syncthreads();
  {
    unsigned short u = ((const unsigned short*)x)[threadIdx.x];
    int e = (u >> 7) & 0xFF;
    atomicAdd(&csh, (u == 0) || (e >= 100 && e <= 145));
  }
  __syncthreads();
  int isf = (csh < 240);

  int b = blockIdx.x;
  if (b < nCvt8) {
    if (!isf) return;                       // bf16 input: x used directly
    int i = b * 256 + threadIdx.x;
    if (i >= n8) return;
    const float* s = (const float*)x + (size_t)i * 8;
    ushort4 a, c;
    a.x = f2bf(s[0]); a.y = f2bf(s[1]); a.z = f2bf(s[2]); a.w = f2bf(s[3]);
    c.x = f2bf(s[4]); c.y = f2bf(s[5]); c.z = f2bf(s[6]); c.w = f2bf(s[7]);
    ((ushort4*)x_c)[i * 2] = a;
    ((ushort4*)x_c)[i * 2 + 1] = c;
    return;
  }
  b -= nCvt8;
  if (b < 10) {
    if (b == 0) {
      if (threadIdx.x == 0) dflag[0] = isf;
      if (threadIdx.x >= 240) colx[ET + (threadIdx.x - 240)] = 0;  // 16-entry pad
    }
    int i = threadIdx.x;
    if (i < segs.len[b]) {
      float v = isf ? ((const float*)segs.src[b])[i]
                    : bf2f(((const unsigned short*)segs.src[b])[i]);
      segs.dst[b][i] = f2bf(v);
      // scaled f32 attention coefficients (exp2-domain scores)
      if (b == 2) att1s[i] = v * ATT_SCALE;
      if (b == 6) att2s[i] = v * ATT_SCALE;
    }
    return;
  }
  b -= 10;
  if (b < nTransB) {
    int idx = b * 256 + threadIdx.x;  // flat over 98304 elements
    const void* src; unsigned short* dst; int R, C, loc;
    if (idx < 32768)      { src = s0; dst = d0; R = 128; C = 256; loc = idx; }
    else if (idx < 65536) { src = s1; dst = d1; R = 128; C = 256; loc = idx - 32768; }
    else if (idx < 81920) { src = s2; dst = d2; R = 256; C = 64;  loc = idx - 65536; }
    else                  { src = s3; dst = d3; R = 256; C = 64;  loc = idx - 81920; }
    unsigned short u = isf ? f2bf(((const float*)src)[loc])
                           : ((const unsigned short*)src)[loc];
    int r = loc / C, cc = loc - r * C;
    dst[cc * R + r] = u;
    return;
  }
  b -= nTransB;
  // histogram: 4 edges per thread (independent atomic chains) [R8-measured]
  int base = b * 1024 + threadIdx.x;
#pragma unroll
  for (int k = 0; k < 4; ++k) {
    int e = base + k * 256;
    if (e < E) atomicAdd(&deg[iclamp(edst[e], 0, N - 1)], 1);
  }
}

// ---------------- scan stage 1: per-1024 block sums (deg+1 self-loop) -------
__global__ __launch_bounds__(1024) void k_scan1(const int* __restrict__ deg, int* bsum, int N) {
  __shared__ int sm[1024];
  int tid = threadIdx.x;
  int i = blockIdx.x * 1024 + tid;
  sm[tid] = (i < N) ? deg[i] + 1 : 0;
  __syncthreads();
  for (int off = 512; off > 0; off >>= 1) {
    if (tid < off) sm[tid] += sm[tid + off];
    __syncthreads();
  }
  if (tid == 0) bsum[blockIdx.x] = sm[0];
}

// ---- scan stage 2: Hillis-Steele + inline bsum prefix -> rowptr & cursor ----
__global__ __launch_bounds__(1024) void k_scan3(const int* __restrict__ deg,
                                                const int* __restrict__ bsum,
                                                int* rowptr, int* cursor, int N) {
  __shared__ int sm[1024];
  __shared__ int boff;
  int tid = threadIdx.x;
  if (tid == 0) {
    int r = 0;
    for (int b = 0; b < blockIdx.x; ++b) r += bsum[b];
    boff = r;
  }
  int i = blockIdx.x * 1024 + tid;
  int v = (i < N) ? deg[i] + 1 : 0;
  sm[tid] = v;
  __syncthreads();
  for (int off = 1; off < 1024; off <<= 1) {
    int t = (tid >= off) ? sm[tid - off] : 0;
    __syncthreads();
    sm[tid] += t;
    __syncthreads();
  }
  if (i < N) {
    int ex = sm[tid] - v + boff;
    rowptr[i] = ex;
    cursor[i] = ex;
    if (i == N - 1) rowptr[N] = ex + v;
  }
}

// ------ dual GEMM body, register-resident B + row loop (PF=1) ------
template <int K, int CT, int RT>
__device__ __forceinline__ void gemm2r_body(
    int bx, int by, int tid,
    const unsigned short* __restrict__ A,
    const unsigned short* __restrict__ BTl, const unsigned short* __restrict__ BTr,
    const unsigned short* __restrict__ bl, const unsigned short* __restrict__ br,
    unsigned short* __restrict__ outl, unsigned short* __restrict__ outr,
    int Nrows, int M) {
  constexpr int KI = K / 32;
  int lane = tid & 63;
  int wave = tid >> 6;
  int r = lane & 15, q = lane >> 4;
  int col0 = by * (4 * CT * 16) + wave * (CT * 16);
  int row0 = bx * (16 * RT);
  short8 Bl[KI][CT], Br[KI][CT];
#pragma unroll
  for (int t = 0; t < CT; ++t) {
    const unsigned short* bpl = BTl + (size_t)(col0 + t * 16 + r) * K + q * 8;
    const unsigned short* bpr = BTr + (size_t)(col0 + t * 16 + r) * K + q * 8;
#pragma unroll
    for (int k = 0; k < KI; ++k) {
      Bl[k][t] = *reinterpret_cast<const short8*>(bpl + k * 32);
      Br[k][t] = *reinterpret_cast<const short8*>(bpr + k * 32);
    }
  }
  float bvl[CT], bvr[CT];
#pragma unroll
  for (int t = 0; t < CT; ++t) {
    bvl[t] = bf2f(bl[col0 + t * 16 + r]);
    bvr[t] = bf2f(br[col0 + t * 16 + r]);
  }
  short8 a[KI], an[KI];
  {
    int ar0 = imin(row0 + r, Nrows - 1);
    const unsigned short* Ap = A + (size_t)ar0 * K + q * 8;
#pragma unroll
    for (int k = 0; k < KI; ++k) a[k] = *reinterpret_cast<const short8*>(Ap + k * 32);
  }
  for (int rt = 0; rt < RT; ++rt) {
    if (rt + 1 < RT) {
      int arn = imin(row0 + (rt + 1) * 16 + r, Nrows - 1);
      const unsigned short* Apn = A + (size_t)arn * K + q * 8;
#pragma unroll
      for (int k = 0; k < KI; ++k) an[k] = *reinterpret_cast<const short8*>(Apn + k * 32);
    }
    floatx4 accl[CT], accr[CT];
#pragma unroll
    for (int t = 0; t < CT; ++t) {
      accl[t] = (floatx4){0.f, 0.f, 0.f, 0.f};
      accr[t] = (floatx4){0.f, 0.f, 0.f, 0.f};
    }
#pragma unroll
    for (int k = 0; k < KI; ++k) {
#pragma unroll
      for (int t = 0; t < CT; ++t) {
        accl[t] = __builtin_amdgcn_mfma_f32_16x16x32_bf16(a[k], Bl[k][t], accl[t], 0, 0, 0);
        accr[t] = __builtin_amdgcn_mfma_f32_16x16x32_bf16(a[k], Br[k][t], accr[t], 0, 0, 0);
      }
    }
#pragma unroll
    for (int t = 0; t < CT; ++t) {
      int col = col0 + t * 16 + r;
#pragma unroll
      for (int rr = 0; rr < 4; ++rr) {
        int row = row0 + rt * 16 + q * 4 + rr;
        if (row < Nrows) {
          outl[(size_t)row * M + col] = f2bf(accl[t][rr] + bvl[t]);
          outr[(size_t)row * M + col] = f2bf(accr[t][rr] + bvr[t]);
        }
      }
    }
#pragma unroll
    for (int k = 0; k < KI; ++k) a[k] = an[k];
  }
}

// ------ phase1: INTERLEAVED layer-1 GEMM || scatter (role by block parity) ----
__global__ __launch_bounds__(256) void k_phase1(
    const unsigned short* __restrict__ A0, const unsigned short* __restrict__ A1,
    const int* __restrict__ dflag,
    const unsigned short* __restrict__ BTl, const unsigned short* __restrict__ BTr,
    const unsigned short* __restrict__ bl, const unsigned short* __restrict__ br,
    unsigned short* __restrict__ outl, unsigned short* __restrict__ outr,
    int Nrows, int M, int nG, int nS,
    const int* __restrict__ esrc, const int* __restrict__ edst,
    const int* __restrict__ rowptr, int* cursor, int* colx, int E, int N) {
  int b = blockIdx.x;
  int m2 = 2 * imin(nG, nS);
  bool isG;
  int idx;
  if (b < m2) { isG = (b & 1) == 0; idx = b >> 1; }
  else        { isG = nG > nS;      idx = imin(nG, nS) + (b - m2); }
  if (isG) {
    const unsigned short* A = dflag[0] ? A1 : A0;
    gemm2r_body<128, 2, 8>(idx >> 1, idx & 1, threadIdx.x, A, BTl, BTr, bl, br,
                           outl, outr, Nrows, M);
    return;
  }
  // scatter: 4 edges per thread (independent atomic chains)
  int ET = E + N;
  int base = idx * 1024 + threadIdx.x;
#pragma unroll
  for (int k = 0; k < 4; ++k) {
    int e = base + k * 256;
    if (e < ET) {
      if (e < E) {
        int s = iclamp(esrc[e], 0, N - 1), d = iclamp(edst[e], 0, N - 1);
        int pos = atomicAdd(&cursor[d], 1);
        colx[iclamp(pos, 0, ET - 1)] = s;
      } else {
        int i = e - E;                 // self-loop: fixed last slot, no atomic
        colx[rowptr[i + 1] - 1] = i;
      }
    }
  }
}

// ---------------- layer-2 GEMM ----------------
__global__ __launch_bounds__(256) void k_gemm2r_l2(
    const unsigned short* __restrict__ A,
    const unsigned short* __restrict__ BTl, const unsigned short* __restrict__ BTr,
    const unsigned short* __restrict__ bl, const unsigned short* __restrict__ br,
    unsigned short* __restrict__ outl, unsigned short* __restrict__ outr,
    int Nrows, int M) {
  gemm2r_body<256, 1, 4>(blockIdx.x, 0, threadIdx.x, A, BTl, BTr, bl, br,
                         outl, outr, Nrows, M);
}

// Packed-f32 per-edge score: unpack uint2 -> two f32x2; q = pk_fma(a, v, ad);
// p = sum(q_k + c_k*|q_k|) via pk_max(|.|) + pk_fma + pk_add. VOP3P executes
// 2 f32 lanes per instruction -> ~40% fewer VALU ops on the score chain.
#define EDGE_P(U, V01, V23, P)                                                \
  V01 = (f32x2){uasf(U.x << 16), uasf(U.x & 0xffff0000u)};                    \
  V23 = (f32x2){uasf(U.y << 16), uasf(U.y & 0xffff0000u)};                    \
  {                                                                           \
    f32x2 q01 = a01 * V01 + ad01;                                             \
    f32x2 q23 = a23 * V23 + ad23;                                             \
    f32x2 t01 = c01 * absv2(q01) + q01;                                       \
    f32x2 t23 = c23 * absv2(q23) + q23;                                       \
    f32x2 sv = t01 + t23;                                                     \
    P = sv[0] + sv[1];                                                        \
  }

#define EDGE_ACC(W, V01, V23)                                                 \
  {                                                                           \
    f32x2 wv = {W, W};                                                        \
    o01 = wv * V01 + o01;                                                     \
    o23 = wv * V23 + o23;                                                     \
  }

// ------- layer-1 aggregation: H=4, C=64, one wave per dst, 4-edge unroll -----
// colx indices prefetched TWO chunks ahead (R0-proven structure); natural dst
// order; packed-f32 math + exp2-domain scores are the only changes.
__global__ __launch_bounds__(256) void k_agg_h4(
    const int* __restrict__ rowptr, const int* __restrict__ colx,
    const unsigned short* __restrict__ xs, const unsigned short* __restrict__ xd,
    const float* __restrict__ atts, const unsigned short* __restrict__ bias,
    unsigned short* __restrict__ hout, int N) {
  int lane = threadIdx.x & 63;
  int dst = (blockIdx.x * 256 + threadIdx.x) >> 6;
  if (dst >= N) return;
  int off = lane << 2;
  unsigned int off2 = (unsigned int)off * 2;
  const char* xsb = (const char*)xs;
  floatx4 av = *reinterpret_cast<const floatx4*>(atts + off);
  ushort4 du = *reinterpret_cast<const ushort4*>(xd + (size_t)dst * 256 + off);
  f32x2 a01 = {av[0], av[1]}, a23 = {av[2], av[3]};
  f32x2 dd01 = {bf2f(du.x), bf2f(du.y)}, dd23 = {bf2f(du.z), bf2f(du.w)};
  f32x2 ad01 = a01 * dd01, ad23 = a23 * dd23;
  f32x2 c01 = {copysignf(C_ABS, av[0]), copysignf(C_ABS, av[1])};
  f32x2 c23 = {copysignf(C_ABS, av[2]), copysignf(C_ABS, av[3])};
  float l = 0.f;
  f32x2 o01 = {0.f, 0.f}, o23 = {0.f, 0.f};
  int beg = __builtin_amdgcn_readfirstlane(rowptr[dst]);
  int end = __builtin_amdgcn_readfirstlane(rowptr[dst + 1]);
  // chunk 0 indices + gathers; chunk 1 indices (colx padded by 16: reads past
  // `end` hit next-row entries or pad zeros -> valid node indices, killed by
  // the -INF tail mask)
  int p0 = colx[beg], p1 = colx[beg + 1], p2 = colx[beg + 2], p3 = colx[beg + 3];
  uint2 ua = *(const uint2*)(xsb + (((unsigned)p0 << 9) + off2));
  uint2 ub = *(const uint2*)(xsb + (((unsigned)p1 << 9) + off2));
  uint2 uc = *(const uint2*)(xsb + (((unsigned)p2 << 9) + off2));
  uint2 ud = *(const uint2*)(xsb + (((unsigned)p3 << 9) + off2));
  int q0 = 0, q1 = 0, q2 = 0, q3 = 0;
  if (beg + 4 < end) {
    q0 = colx[beg + 4]; q1 = colx[beg + 5]; q2 = colx[beg + 6]; q3 = colx[beg + 7];
  }
  for (int e = beg; e < end; e += 4) {
    uint2 na = ua, nb = ub, nc = uc, nd = ud;
    if (e + 4 < end) {       // gathers from indices loaded 2 chunks ago
      na = *(const uint2*)(xsb + (((unsigned)q0 << 9) + off2));
      nb = *(const uint2*)(xsb + (((unsigned)q1 << 9) + off2));
      nc = *(const uint2*)(xsb + (((unsigned)q2 << 9) + off2));
      nd = *(const uint2*)(xsb + (((unsigned)q3 << 9) + off2));
    }
    if (e + 8 < end) {       // indices for chunk i+2 load under compute
      q0 = colx[e + 8]; q1 = colx[e + 9]; q2 = colx[e + 10]; q3 = colx[e + 11];
    }
    f32x2 va01, va23, vb01, vb23, vc01, vc23, vd01, vd23;
    float pa, pb, pc, pd;
    EDGE_P(ua, va01, va23, pa)
    EDGE_P(ub, vb01, vb23, pb)
    EDGE_P(uc, vc01, vc23, pc)
    EDGE_P(ud, vd01, vd23, pd)
    pa = sum16(pa); pb = sum16(pb); pc = sum16(pc); pd = sum16(pd);
    pa = fminf(pa, PCLAMP);                            // upper clamp only
    pb = (e + 1 < end) ? fminf(pb, PCLAMP) : -INFINITY;
    pc = (e + 2 < end) ? fminf(pc, PCLAMP) : -INFINITY;
    pd = (e + 3 < end) ? fminf(pd, PCLAMP) : -INFINITY;
    float wa = exp2fast(pa), wb = exp2fast(pb);
    float wc = exp2fast(pc), wd = exp2fast(pd);
    l += (wa + wb) + (wc + wd);
    EDGE_ACC(wa, va01, va23)
    EDGE_ACC(wb, vb01, vb23)
    EDGE_ACC(wc, vc01, vc23)
    EDGE_ACC(wd, vd01, vd23)
    ua = na; ub = nb; uc = nc; ud = nd;
  }
  float rl = 1.0f / l;
  ushort4 bu = *reinterpret_cast<const ushort4*>(bias + off);
  ushort4 res;
  res.x = f2bf(fmaxf(fmaf(o01[0], rl, bf2f(bu.x)), 0.f));
  res.y = f2bf(fmaxf(fmaf(o01[1], rl, bf2f(bu.y)), 0.f));
  res.z = f2bf(fmaxf(fmaf(o23[0], rl, bf2f(bu.z)), 0.f));
  res.w = f2bf(fmaxf(fmaf(o23[1], rl, bf2f(bu.w)), 0.f));
  *reinterpret_cast<ushort4*>(hout + (size_t)dst * 256 + off) = res;
}

// ------- layer-2 aggregation: H=1, C=64, 4 dst/wave, 4-edge unroll ---------
__global__ __launch_bounds__(256) void k_agg_h1(
    const int* __restrict__ rowptr, const int* __restrict__ colx,
    const unsigned short* __restrict__ xs, const unsigned short* __restrict__ xd,
    const float* __restrict__ atts, const unsigned short* __restrict__ bias,
    float* __restrict__ hout, int N) {
  int lane = threadIdx.x & 63;
  int wid = (blockIdx.x * 256 + threadIdx.x) >> 6;
  int g = lane >> 4, sl = lane & 15;
  int dst = wid * 4 + g;
  bool valid = dst < N;
  int dsafe = valid ? dst : 0;
  int cb = sl << 2;
  unsigned int cb2 = (unsigned int)cb * 2;
  const char* xsb = (const char*)xs;
  floatx4 av = *reinterpret_cast<const floatx4*>(atts + cb);
  ushort4 du = *reinterpret_cast<const ushort4*>(xd + (size_t)dsafe * 64 + cb);
  f32x2 a01 = {av[0], av[1]}, a23 = {av[2], av[3]};
  f32x2 dd01 = {bf2f(du.x), bf2f(du.y)}, dd23 = {bf2f(du.z), bf2f(du.w)};
  f32x2 ad01 = a01 * dd01, ad23 = a23 * dd23;
  f32x2 c01 = {copysignf(C_ABS, av[0]), copysignf(C_ABS, av[1])};
  f32x2 c23 = {copysignf(C_ABS, av[2]), copysignf(C_ABS, av[3])};
  float l = 0.f;
  f32x2 o01 = {0.f, 0.f}, o23 = {0.f, 0.f};
  int beg = valid ? rowptr[dst] : 0;
  int end = valid ? rowptr[dst + 1] : 0;
  if (end > beg) {
    int p0 = colx[beg], p1 = colx[beg + 1], p2 = colx[beg + 2], p3 = colx[beg + 3];
    uint2 ua = *(const uint2*)(xsb + (((unsigned)p0 << 7) + cb2));
    uint2 ub = *(const uint2*)(xsb + (((unsigned)p1 << 7) + cb2));
    uint2 uc = *(const uint2*)(xsb + (((unsigned)p2 << 7) + cb2));
    uint2 ud = *(const uint2*)(xsb + (((unsigned)p3 << 7) + cb2));
    int q0 = 0, q1 = 0, q2 = 0, q3 = 0;
    if (beg + 4 < end) {
      q0 = colx[beg + 4]; q1 = colx[beg + 5]; q2 = colx[beg + 6]; q3 = colx[beg + 7];
    }
    for (int e = beg; e < end; e += 4) {
      uint2 na = ua, nb = ub, nc = uc, nd = ud;
      if (e + 4 < end) {
        na = *(const uint2*)(xsb + (((unsigned)q0 << 7) + cb2));
        nb = *(const uint2*)(xsb + (((unsigned)q1 << 7) + cb2));
        nc = *(const uint2*)(xsb + (((unsigned)q2 << 7) + cb2));
        nd = *(const uint2*)(xsb + (((unsigned)q3 << 7) + cb2));
      }
      if (e + 8 < end) {
        q0 = colx[e + 8]; q1 = colx[e + 9]; q2 = colx[e + 10]; q3 = colx[e + 11];
      }
      f32x2 va01, va23, vb01, vb23, vc01, vc23, vd01, vd23;
      float pa, pb, pc, pd;
      EDGE_P(ua, va01, va23, pa)
      EDGE_P(ub, vb01, vb23, pb)
      EDGE_P(uc, vc01, vc23, pc)
      EDGE_P(ud, vd01, vd23, pd)
      pa = sum16(pa); pb = sum16(pb); pc = sum16(pc); pd = sum16(pd);
      pa = fminf(pa, PCLAMP);
      pb = (e + 1 < end) ? fminf(pb, PCLAMP) : -INFINITY;
      pc = (e + 2 < end) ? fminf(pc, PCLAMP) : -INFINITY;
      pd = (e + 3 < end) ? fminf(pd, PCLAMP) : -INFINITY;
      float wa = exp2fast(pa), wb = exp2fast(pb);
      float wc = exp2fast(pc), wd = exp2fast(pd);
      l += (wa + wb) + (wc + wd);
      EDGE_ACC(wa, va01, va23)
      EDGE_ACC(wb, vb01, vb23)
      EDGE_ACC(wc, vc01, vc23)
      EDGE_ACC(wd, vd01, vd23)
      ua = na; ub = nb; uc = nc; ud = nd;
    }
  }
  if (valid) {
    float rl = 1.0f / l;
    ushort4 bu = *reinterpret_cast<const ushort4*>(bias + cb);
    floatx4 res;
    res[0] = fmaf(o01[0], rl, bf2f(bu.x));
    res[1] = fmaf(o01[1], rl, bf2f(bu.y));
    res[2] = fmaf(o23[0], rl, bf2f(bu.z));
    res[3] = fmaf(o23[1], rl, bf2f(bu.w));
    *reinterpret_cast<floatx4*>(hout + (size_t)dst * 64 + cb) = res;
  }
}

// ---------------- mean pool over sorted batch [R8-measured] ----------------
__global__ __launch_bounds__(256) void k_pool(const float* __restrict__ h2,
                                              const int* __restrict__ batch,
                                              float* pool, int* cnt, int N) {
  int lane = threadIdx.x & 63;
  int wid = (blockIdx.x * 256 + threadIdx.x) >> 6;
  int n0 = wid * 32;
  if (n0 >= N) return;
  int nend = imin(n0 + 32, N);
  float acc = 0.f;
  int c = 0;
  int gcur = iclamp(batch[n0], 0, 63);
  for (int n = n0; n < nend; ++n) {
    int gg = iclamp(batch[n], 0, 63);
    if (gg != gcur) {
      atomicAdd(&pool[gcur * 64 + lane], acc);
      if (lane == 0) atomicAdd(&cnt[gcur], c);
      acc = 0.f; c = 0; gcur = gg;
    }
    acc += h2[(size_t)n * 64 + lane];
    c++;
  }
  atomicAdd(&pool[gcur * 64 + lane], acc);
  if (lane == 0) atomicAdd(&cnt[gcur], c);
}

// ---------------- final ----------------
__global__ void k_final(const float* __restrict__ pool, const int* __restrict__ cnt,
                        const unsigned short* __restrict__ Wlinc,
                        const unsigned short* __restrict__ blinc,
                        float* __restrict__ out) {
  int g = threadIdx.x;
  if (g >= 64) return;
  float inv = 1.f / fmaxf((float)cnt[g], 1.f);
  float s = 0.f;
  for (int c = 0; c < 64; ++c) s += pool[g * 64 + c] * bf2f(Wlinc[c]);
  out[g] = fmaf(s, inv, bf2f(blinc[0]));
}

extern "C" void kernel_launch(void* const* d_in, const int* in_sizes, int n_in,
                              void* d_out, int out_size, void* d_ws, size_t ws_size,
                              hipStream_t stream) {
  const void* x     = d_in[0];
  const int*  ei    = (const int*)d_in[1];
  const int*  batch = (const int*)d_in[2];
  const void* Wl1 = d_in[3];  const void* bl1 = d_in[4];
  const void* Wr1 = d_in[5];  const void* br1 = d_in[6];
  const void* att1 = d_in[7]; const void* bias1 = d_in[8];
  const void* Wl2 = d_in[9];  const void* bl2 = d_in[10];
  const void* Wr2 = d_in[11]; const void* br2 = d_in[12];
  const void* att2 = d_in[13]; const void* bias2 = d_in[14];
  const void* Wlin = d_in[15]; const void* blin = d_in[16];
  float* out = (float*)d_out;

  const int F = 128, HC = 256, C2 = 64;
  int N = in_sizes[0] / F;
  int E = in_sizes[1] / 2;
  int ET = E + N;
  const int* esrc = ei;
  const int* edst = ei + E;

  // ---- workspace carve-up ----
  char* w = (char*)d_ws;
  auto alloc = [&](size_t bytes) {
    char* p = w;
    w += (bytes + 255) & ~(size_t)255;
    return p;
  };
  int* dflag  = (int*)alloc(4);
  int* rowptr = (int*)alloc((size_t)(N + 1) * 4);
  int* cursor = (int*)alloc((size_t)N * 4);
  int* bsum   = (int*)alloc(1024 * 4);
  int* colx   = (int*)alloc((size_t)(ET + 16) * 4);
  unsigned short* smallc = (unsigned short*)alloc(4096);
  float* att1s = (float*)alloc(256 * 4);
  float* att2s = (float*)alloc(64 * 4);
  unsigned short* Wl1T = (unsigned short*)alloc((size_t)F * HC * 2);
  unsigned short* Wr1T = (unsigned short*)alloc((size_t)F * HC * 2);
  unsigned short* Wl2T = (unsigned short*)alloc((size_t)HC * C2 * 2);
  unsigned short* Wr2T = (unsigned short*)alloc((size_t)HC * C2 * 2);
  int* deg    = (int*)alloc((size_t)N * 4);     // zero-region start
  float* pool = (float*)alloc(64 * 64 * 4);
  int* cnt    = (int*)alloc(64 * 4);            // zero-region end
  unsigned short* xs1  = (unsigned short*)alloc((size_t)N * HC * 2);
  unsigned short* xd1  = (unsigned short*)alloc((size_t)N * HC * 2);
  unsigned short* h1   = (unsigned short*)alloc((size_t)N * HC * 2);
  size_t required = (size_t)(w - (char*)d_ws);
  size_t zlen = (size_t)((char*)cnt + 256 - (char*)deg);

  unsigned short* x_c = h1;
  unsigned short* xs2 = xs1;
  unsigned short* xd2 = xs1 + (size_t)N * C2;
  float*          h2  = (float*)xd1;

  unsigned short* bl1c   = smallc + 0;
  unsigned short* br1c   = smallc + 256;
  unsigned short* att1c  = smallc + 512;
  unsigned short* bias1c = smallc + 768;
  unsigned short* bl2c   = smallc + 1024;
  unsigned short* br2c   = smallc + 1088;
  unsigned short* att2c  = smallc + 1152;
  unsigned short* bias2c = smallc + 1216;
  unsigned short* Wlinc  = smallc + 1280;
  unsigned short* blinc  = smallc + 1344;

  if (ws_size < required) {
    k_sentinel<<<1, 64, 0, stream>>>(out, 1000.f + (float)(ws_size >> 20));
    return;
  }

  hipMemsetAsync(deg, 0, zlen, stream);

  // ---- mega prep: probe | cvt8 | small cvts | transposes | hist(4/thread) ----
  CvtSegs segs;
  const void* ssrc[10] = {bl1, br1, att1, bias1, bl2, br2, att2, bias2, Wlin, blin};
  unsigned short* sdst[10] = {bl1c, br1c, att1c, bias1c, bl2c, br2c, att2c, bias2c, Wlinc, blinc};
  int slen[10] = {256, 256, 256, 256, 64, 64, 64, 64, 64, 1};
  for (int i = 0; i < 10; ++i) { segs.src[i] = ssrc[i]; segs.dst[i] = sdst[i]; segs.len[i] = slen[i]; }
  int n8 = N * F / 8;
  int nCvt8 = (n8 + 255) / 256;
  int nTransB = (2 * F * HC + 2 * HC * C2 + 255) / 256;
  int nHist = (E + 1023) / 1024;
  k_prep<<<nCvt8 + 10 + nTransB + nHist, 256, 0, stream>>>(
      x, x_c, n8, segs, Wl1, Wr1, Wl2, Wr2, Wl1T, Wr1T, Wl2T, Wr2T,
      edst, deg, E, N, dflag, colx, ET, att1s, att2s, nCvt8, nTransB);

  // ---- scan ----
  int nb = (N + 1023) / 1024;
  k_scan1<<<nb, 1024, 0, stream>>>(deg, bsum, N);
  k_scan3<<<nb, 1024, 0, stream>>>(deg, bsum, rowptr, cursor, N);

  // ---- phase1: interleaved layer-1 GEMM || scatter ----
  int nG = ((N + 127) / 128) * 2;
  int nS = (ET + 1023) / 1024;
  k_phase1<<<nG + nS, 256, 0, stream>>>(
      (const unsigned short*)x, x_c, dflag, Wl1T, Wr1T, bl1c, br1c, xs1, xd1,
      N, HC, nG, nS, esrc, edst, rowptr, cursor, colx, E, N);

  // ---- layer 1 aggregation ----
  k_agg_h4<<<(N + 3) / 4, 256, 0, stream>>>(rowptr, colx, xs1, xd1, att1s, bias1c, h1, N);

  // ---- layer 2 ----
  k_gemm2r_l2<<<(N + 63) / 64, 256, 0, stream>>>(h1, Wl2T, Wr2T, bl2c, br2c, xs2, xd2, N, C2);
  k_agg_h1<<<(N + 15) / 16, 256, 0, stream>>>(rowptr, colx, xs2, xd2, att2s, bias2c, h2, N);

  // ---- pool + final ----
  int pw = (N + 31) / 32;
  k_pool<<<(pw + 3) / 4, 256, 0, stream>>>(h2, batch, pool, cnt, N);
  k_final<<<1, 64, 0, stream>>>(pool, cnt, Wlinc, blinc, out);
}